// Round 3
// baseline (438.230 us; speedup 1.0000x reference)
//
#include <hip/hip_runtime.h>
#include <hip/hip_bf16.h>
#include <math.h>

typedef __bf16 bf16;
typedef bf16 bf16x8 __attribute__((ext_vector_type(8)));
typedef float floatx4 __attribute__((ext_vector_type(4)));

#define MFMA16(a, b, c) __builtin_amdgcn_mfma_f32_16x16x32_bf16(a, b, c, 0, 0, 0)

__device__ __forceinline__ void split2(float v, bf16& h, bf16& l) {
    h = (bf16)v;
    l = (bf16)(v - (float)h);
}

// ---------------------------------------------------------------------------
// K0a: split x fp32 -> hi/lo bf16 (same layout)
// ---------------------------------------------------------------------------
__global__ void split_x(const float* __restrict__ x, bf16* __restrict__ xh,
                        bf16* __restrict__ xl) {
    const int i = (blockIdx.x * 256 + threadIdx.x) * 8;
    float4 a = *(const float4*)(x + i);
    float4 b = *(const float4*)(x + i + 4);
    bf16x8 oh, ol;
    float f[8] = {a.x, a.y, a.z, a.w, b.x, b.y, b.z, b.w};
#pragma unroll
    for (int j = 0; j < 8; j++) { bf16 h, l; split2(f[j], h, l); oh[j] = h; ol[j] = l; }
    *(bf16x8*)(xh + i) = oh;
    *(bf16x8*)(xl + i) = ol;
}

// ---------------------------------------------------------------------------
// K0b: transpose+split the 4 fp32 weights [1024][1024] W[k][n] -> hi/lo bf16 Wt[n][k]
// ---------------------------------------------------------------------------
__global__ void transpose_w(const float* __restrict__ wq, const float* __restrict__ wk,
                            const float* __restrict__ wv, const float* __restrict__ wo,
                            bf16* __restrict__ wt_qkv_h, bf16* __restrict__ wt_qkv_l,
                            bf16* __restrict__ wt_o_h, bf16* __restrict__ wt_o_l) {
    const int z = blockIdx.z;
    const float* src = (z == 0) ? wq : (z == 1) ? wk : (z == 2) ? wv : wo;
    bf16* dsth = (z < 3) ? (wt_qkv_h + (size_t)z * 1024 * 1024) : wt_o_h;
    bf16* dstl = (z < 3) ? (wt_qkv_l + (size_t)z * 1024 * 1024) : wt_o_l;
    __shared__ float tile[32][33];
    const int x0 = blockIdx.x * 32, y0 = blockIdx.y * 32;
    const int tx = threadIdx.x, ty = threadIdx.y;  // (32,8)
    for (int i = 0; i < 32; i += 8)
        tile[ty + i][tx] = src[(size_t)(y0 + ty + i) * 1024 + x0 + tx];
    __syncthreads();
    for (int i = 0; i < 32; i += 8) {
        bf16 h, l;
        split2(tile[tx][ty + i], h, l);
        dsth[(size_t)(x0 + ty + i) * 1024 + y0 + tx] = h;
        dstl[(size_t)(x0 + ty + i) * 1024 + y0 + tx] = l;
    }
}

// ---------------------------------------------------------------------------
// K1: fused QKV GEMM, 3-pass split-bf16 (fp32-accurate): C = A * Bt^T + bias
// A = x (hi/lo), Bt = stacked wq|wk|wv transposed (hi/lo). N=3072.
// Q,K written as hi/lo bf16 pairs [B,H,S,D]; V as single bf16.
// ---------------------------------------------------------------------------
__global__ __launch_bounds__(256, 2) void gemm_qkv3(
    const bf16* __restrict__ Ah, const bf16* __restrict__ Al,
    const bf16* __restrict__ Bth, const bf16* __restrict__ Btl,
    const float* __restrict__ bq, const float* __restrict__ bk,
    const float* __restrict__ bv,
    bf16* __restrict__ Qh, bf16* __restrict__ Ql,
    bf16* __restrict__ Kh, bf16* __restrict__ Kl, bf16* __restrict__ Vb) {
    __shared__ bf16 Ash[128 * 40];
    __shared__ bf16 Asl[128 * 40];
    __shared__ bf16 Bsh[128 * 40];
    __shared__ bf16 Bsl[128 * 40];

    const int t = threadIdx.x;
    const int lane = t & 63, wave = t >> 6;
    const int quad = lane >> 4, l16 = lane & 15;
    const int m0 = blockIdx.x * 128, n0 = blockIdx.y * 128;
    const int wm = (wave >> 1) * 64, wn = (wave & 1) * 64;

    const int srow = t >> 2;        // 0..63
    const int scol = (t & 3) * 8;   // 0/8/16/24
    const bf16* gAh = Ah + (size_t)(m0 + srow) * 1024 + scol;
    const bf16* gAl = Al + (size_t)(m0 + srow) * 1024 + scol;
    const bf16* gBh = Bth + (size_t)(n0 + srow) * 1024 + scol;
    const bf16* gBl = Btl + (size_t)(n0 + srow) * 1024 + scol;

    floatx4 acc[4][4] = {};

    for (int k0 = 0; k0 < 1024; k0 += 32) {
        bf16x8 rah0 = *(const bf16x8*)(gAh + k0);
        bf16x8 rah1 = *(const bf16x8*)(gAh + 64 * 1024 + k0);
        bf16x8 ral0 = *(const bf16x8*)(gAl + k0);
        bf16x8 ral1 = *(const bf16x8*)(gAl + 64 * 1024 + k0);
        bf16x8 rbh0 = *(const bf16x8*)(gBh + k0);
        bf16x8 rbh1 = *(const bf16x8*)(gBh + 64 * 1024 + k0);
        bf16x8 rbl0 = *(const bf16x8*)(gBl + k0);
        bf16x8 rbl1 = *(const bf16x8*)(gBl + 64 * 1024 + k0);
        __syncthreads();
        *(bf16x8*)&Ash[srow * 40 + scol] = rah0;
        *(bf16x8*)&Ash[(64 + srow) * 40 + scol] = rah1;
        *(bf16x8*)&Asl[srow * 40 + scol] = ral0;
        *(bf16x8*)&Asl[(64 + srow) * 40 + scol] = ral1;
        *(bf16x8*)&Bsh[srow * 40 + scol] = rbh0;
        *(bf16x8*)&Bsh[(64 + srow) * 40 + scol] = rbh1;
        *(bf16x8*)&Bsl[srow * 40 + scol] = rbl0;
        *(bf16x8*)&Bsl[(64 + srow) * 40 + scol] = rbl1;
        __syncthreads();
        bf16x8 afh[4], afl[4], bfh[4], bfl[4];
#pragma unroll
        for (int i = 0; i < 4; i++) {
            afh[i] = *(bf16x8*)&Ash[(wm + i * 16 + l16) * 40 + quad * 8];
            afl[i] = *(bf16x8*)&Asl[(wm + i * 16 + l16) * 40 + quad * 8];
        }
#pragma unroll
        for (int j = 0; j < 4; j++) {
            bfh[j] = *(bf16x8*)&Bsh[(wn + j * 16 + l16) * 40 + quad * 8];
            bfl[j] = *(bf16x8*)&Bsl[(wn + j * 16 + l16) * 40 + quad * 8];
        }
#pragma unroll
        for (int i = 0; i < 4; i++)
#pragma unroll
            for (int j = 0; j < 4; j++) {
                acc[i][j] = MFMA16(afh[i], bfh[j], acc[i][j]);
                acc[i][j] = MFMA16(afh[i], bfl[j], acc[i][j]);
                acc[i][j] = MFMA16(afl[i], bfh[j], acc[i][j]);
            }
    }

    const int which = n0 >> 10;  // 0=Q 1=K 2=V (128 | 1024, never straddles)
    const float* bias = (which == 0) ? bq : (which == 1) ? bk : bv;
#pragma unroll
    for (int i = 0; i < 4; i++)
#pragma unroll
        for (int j = 0; j < 4; j++) {
            const int col = n0 + wn + j * 16 + l16;
            const int o = col & 1023;
            const int h = o >> 6, d = o & 63;
            const float bvv = bias[o];
#pragma unroll
            for (int r = 0; r < 4; r++) {
                const int gm = m0 + wm + i * 16 + quad * 4 + r;  // token id
                const int b = gm >> 11, s = gm & 2047;
                const size_t idx = (size_t)((b * 16 + h) * 2048 + s) * 64 + d;
                const float val = acc[i][j][r] + bvv;
                if (which == 2) {
                    Vb[idx] = (bf16)val;
                } else {
                    bf16 hi, lo;
                    split2(val, hi, lo);
                    if (which == 0) { Qh[idx] = hi; Ql[idx] = lo; }
                    else            { Kh[idx] = hi; Kl[idx] = lo; }
                }
            }
        }
}

// ---------------------------------------------------------------------------
// K2: flash attention, YAT scores, split-precision QK^T
//   scores = sc * dot^2 / (||q||^2+||k||^2-2dot+eps), online softmax, O = P*V
// Block: 256 thr = 4 waves; each wave owns 16 q-rows; block = 64 q-rows.
// ---------------------------------------------------------------------------
__global__ __launch_bounds__(256, 2) void attn_kernel(
    const bf16* __restrict__ Qh, const bf16* __restrict__ Ql,
    const bf16* __restrict__ Kh, const bf16* __restrict__ Kl,
    const bf16* __restrict__ V, bf16* __restrict__ O,
    const float* __restrict__ alphap) {
    __shared__ bf16 Ksh[64 * 72];     // [key][d] hi
    __shared__ bf16 Ksl[64 * 72];     // [key][d] lo
    __shared__ bf16 Vt[64 * 72];      // [d][key] (transposed at staging)
    __shared__ bf16 Ps[4][16 * 72];   // per-wave P tile [qrow][key]
    __shared__ float qn_s[64], kn_s[64];

    const int t = threadIdx.x, lane = t & 63, wave = t >> 6;
    const int quad = lane >> 4, l16 = lane & 15;
    const int bh = blockIdx.x;       // b*16+h
    const int q0 = blockIdx.y * 64;

    const size_t qbase = (size_t)(bh * 2048 + q0) * 64;
    const float alpha = alphap[0];
    const float sc = powf(8.0f / log1pf(64.0f), alpha);

    // Q A-fragments (hi+lo): m = l16, k(=d) = quad*8+j
    const size_t qrow = qbase + (size_t)(wave * 16 + l16) * 64;
    const bf16x8 aq0h = *(const bf16x8*)(Qh + qrow + quad * 8);
    const bf16x8 aq1h = *(const bf16x8*)(Qh + qrow + 32 + quad * 8);
    const bf16x8 aq0l = *(const bf16x8*)(Ql + qrow + quad * 8);
    const bf16x8 aq1l = *(const bf16x8*)(Ql + qrow + 32 + quad * 8);

    if (t < 64) {  // ||q||^2 from hi+lo (fp32-accurate)
        float s = 0.f;
        for (int d0 = 0; d0 < 64; d0 += 8) {
            bf16x8 vh = *(const bf16x8*)(Qh + qbase + (size_t)t * 64 + d0);
            bf16x8 vl = *(const bf16x8*)(Ql + qbase + (size_t)t * 64 + d0);
            for (int j = 0; j < 8; j++) {
                float x = (float)vh[j] + (float)vl[j];
                s += x * x;
            }
        }
        qn_s[t] = s;
    }
    __syncthreads();
    float qn_v[4];
#pragma unroll
    for (int r = 0; r < 4; r++) qn_v[r] = qn_s[wave * 16 + quad * 4 + r];

    floatx4 acco[4] = {};
    float m_i[4] = {-1e30f, -1e30f, -1e30f, -1e30f};
    float l_i[4] = {0.f, 0.f, 0.f, 0.f};

    const int srow = t >> 3;        // 0..31
    const int scol = (t & 7) * 8;   // 0..56

    for (int kc = 0; kc < 2048; kc += 64) {
        const size_t kbase = (size_t)(bh * 2048 + kc) * 64;
        __syncthreads();  // previous chunk's compute done
        // stage K hi/lo [64][64] -> Ksh/Ksl
        *(bf16x8*)&Ksh[srow * 72 + scol] = *(const bf16x8*)(Kh + kbase + srow * 64 + scol);
        *(bf16x8*)&Ksh[(32 + srow) * 72 + scol] = *(const bf16x8*)(Kh + kbase + (32 + srow) * 64 + scol);
        *(bf16x8*)&Ksl[srow * 72 + scol] = *(const bf16x8*)(Kl + kbase + srow * 64 + scol);
        *(bf16x8*)&Ksl[(32 + srow) * 72 + scol] = *(const bf16x8*)(Kl + kbase + (32 + srow) * 64 + scol);
        // stage V transposed -> Vt[d][key]
        {
            bf16x8 v0 = *(const bf16x8*)(V + kbase + srow * 64 + scol);
            bf16x8 v1 = *(const bf16x8*)(V + kbase + (32 + srow) * 64 + scol);
#pragma unroll
            for (int j = 0; j < 8; j++) Vt[(scol + j) * 72 + srow] = v0[j];
#pragma unroll
            for (int j = 0; j < 8; j++) Vt[(scol + j) * 72 + 32 + srow] = v1[j];
        }
        __syncthreads();
        if (t < 64) {  // ||k||^2 from hi+lo
            float s = 0.f;
            for (int d0 = 0; d0 < 64; d0 += 8) {
                bf16x8 vh = *(const bf16x8*)&Ksh[t * 72 + d0];
                bf16x8 vl = *(const bf16x8*)&Ksl[t * 72 + d0];
                for (int j = 0; j < 8; j++) {
                    float x = (float)vh[j] + (float)vl[j];
                    s += x * x;
                }
            }
            kn_s[t] = s;
        }
        __syncthreads();

        // QK^T (split 3-term) -> YAT scores
        float sarr[4][4];  // [key-subtile][r]
#pragma unroll
        for (int sub = 0; sub < 4; sub++) {
            floatx4 accs = {};
            bf16x8 b0h = *(bf16x8*)&Ksh[(sub * 16 + l16) * 72 + quad * 8];
            bf16x8 b1h = *(bf16x8*)&Ksh[(sub * 16 + l16) * 72 + 32 + quad * 8];
            bf16x8 b0l = *(bf16x8*)&Ksl[(sub * 16 + l16) * 72 + quad * 8];
            bf16x8 b1l = *(bf16x8*)&Ksl[(sub * 16 + l16) * 72 + 32 + quad * 8];
            accs = MFMA16(aq0h, b0h, accs);
            accs = MFMA16(aq1h, b1h, accs);
            accs = MFMA16(aq0h, b0l, accs);
            accs = MFMA16(aq1h, b1l, accs);
            accs = MFMA16(aq0l, b0h, accs);
            accs = MFMA16(aq1l, b1h, accs);
            const float kn_v = kn_s[sub * 16 + l16];
#pragma unroll
            for (int r = 0; r < 4; r++) {
                const float dot = accs[r];
                const float d2 = qn_v[r] + kn_v - 2.0f * dot + 1e-5f;
                sarr[sub][r] = sc * dot * dot / d2;
            }
        }

        // online softmax (rows live in this lane's quad: row = quad*4+r)
        bf16* Pw = Ps[wave];
#pragma unroll
        for (int r = 0; r < 4; r++) {
            float mx = fmaxf(fmaxf(sarr[0][r], sarr[1][r]), fmaxf(sarr[2][r], sarr[3][r]));
#pragma unroll
            for (int off = 1; off < 16; off <<= 1) mx = fmaxf(mx, __shfl_xor(mx, off, 64));
            const float mnew = fmaxf(m_i[r], mx);
            const float al = __expf(m_i[r] - mnew);
            float rs = 0.f, p[4];
#pragma unroll
            for (int sub = 0; sub < 4; sub++) { p[sub] = __expf(sarr[sub][r] - mnew); rs += p[sub]; }
#pragma unroll
            for (int off = 1; off < 16; off <<= 1) rs += __shfl_xor(rs, off, 64);
            l_i[r] = l_i[r] * al + rs;
            m_i[r] = mnew;
#pragma unroll
            for (int dsub = 0; dsub < 4; dsub++) acco[dsub][r] *= al;
#pragma unroll
            for (int sub = 0; sub < 4; sub++)
                Pw[(quad * 4 + r) * 72 + sub * 16 + l16] = (bf16)p[sub];
        }

        // P*V accumulate (P via LDS round-trip into A-layout; same-wave, no barrier)
#pragma unroll
        for (int dsub = 0; dsub < 4; dsub++) {
            bf16x8 ap0 = *(bf16x8*)&Pw[l16 * 72 + quad * 8];
            bf16x8 ap1 = *(bf16x8*)&Pw[l16 * 72 + 32 + quad * 8];
            bf16x8 bv0 = *(bf16x8*)&Vt[(dsub * 16 + l16) * 72 + quad * 8];
            bf16x8 bv1 = *(bf16x8*)&Vt[(dsub * 16 + l16) * 72 + 32 + quad * 8];
            acco[dsub] = MFMA16(ap0, bv0, acco[dsub]);
            acco[dsub] = MFMA16(ap1, bv1, acco[dsub]);
        }
    }

    // epilogue: O[b][s][h*64+d] = acco / l   (bf16 activation for out-proj)
    const int b = bh >> 4, h = bh & 15;
#pragma unroll
    for (int dsub = 0; dsub < 4; dsub++)
#pragma unroll
        for (int r = 0; r < 4; r++) {
            const int s = q0 + wave * 16 + quad * 4 + r;
            O[(size_t)(b * 2048 + s) * 1024 + h * 64 + dsub * 16 + l16] =
                (bf16)(acco[dsub][r] / l_i[r]);
        }
}

// ---------------------------------------------------------------------------
// K3: out-proj GEMM (single bf16 pass), fp32 output: out = Ob * wt_o^T + bo
// ---------------------------------------------------------------------------
__global__ __launch_bounds__(256, 2) void gemm_out(
    const bf16* __restrict__ A, const bf16* __restrict__ Bt,
    const float* __restrict__ bias, float* __restrict__ outC) {
    __shared__ bf16 As[128 * 40];
    __shared__ bf16 Bs[128 * 40];

    const int t = threadIdx.x;
    const int lane = t & 63, wave = t >> 6;
    const int quad = lane >> 4, l16 = lane & 15;
    const int m0 = blockIdx.x * 128, n0 = blockIdx.y * 128;
    const int wm = (wave >> 1) * 64, wn = (wave & 1) * 64;

    const int srow = t >> 2;
    const int scol = (t & 3) * 8;
    const bf16* gA0 = A + (size_t)(m0 + srow) * 1024 + scol;
    const bf16* gB0 = Bt + (size_t)(n0 + srow) * 1024 + scol;

    floatx4 acc[4][4] = {};

    for (int k0 = 0; k0 < 1024; k0 += 32) {
        bf16x8 ra0 = *(const bf16x8*)(gA0 + k0);
        bf16x8 ra1 = *(const bf16x8*)(gA0 + 64 * 1024 + k0);
        bf16x8 rb0 = *(const bf16x8*)(gB0 + k0);
        bf16x8 rb1 = *(const bf16x8*)(gB0 + 64 * 1024 + k0);
        __syncthreads();
        *(bf16x8*)&As[srow * 40 + scol] = ra0;
        *(bf16x8*)&As[(64 + srow) * 40 + scol] = ra1;
        *(bf16x8*)&Bs[srow * 40 + scol] = rb0;
        *(bf16x8*)&Bs[(64 + srow) * 40 + scol] = rb1;
        __syncthreads();
        bf16x8 af[4], bf_[4];
#pragma unroll
        for (int i = 0; i < 4; i++)
            af[i] = *(bf16x8*)&As[(wm + i * 16 + l16) * 40 + quad * 8];
#pragma unroll
        for (int j = 0; j < 4; j++)
            bf_[j] = *(bf16x8*)&Bs[(wn + j * 16 + l16) * 40 + quad * 8];
#pragma unroll
        for (int i = 0; i < 4; i++)
#pragma unroll
            for (int j = 0; j < 4; j++)
                acc[i][j] = MFMA16(af[i], bf_[j], acc[i][j]);
    }

#pragma unroll
    for (int i = 0; i < 4; i++)
#pragma unroll
        for (int j = 0; j < 4; j++) {
            const int col = n0 + wn + j * 16 + l16;
            const float bvv = bias[col];
#pragma unroll
            for (int r = 0; r < 4; r++) {
                const int gm = m0 + wm + i * 16 + quad * 4 + r;
                outC[(size_t)gm * 1024 + col] = acc[i][j][r] + bvv;
            }
        }
}

// ---------------------------------------------------------------------------
extern "C" void kernel_launch(void* const* d_in, const int* in_sizes, int n_in,
                              void* d_out, int out_size, void* d_ws, size_t ws_size,
                              hipStream_t stream) {
    const float* x  = (const float*)d_in[0];
    const float* wq = (const float*)d_in[1];
    const float* bq = (const float*)d_in[2];
    const float* wk = (const float*)d_in[3];
    const float* bk = (const float*)d_in[4];
    const float* wv = (const float*)d_in[5];
    const float* bv = (const float*)d_in[6];
    const float* wo = (const float*)d_in[7];
    const float* bo = (const float*)d_in[8];
    const float* alpha = (const float*)d_in[9];

    char* ws = (char*)d_ws;
    const size_t MB = 1024 * 1024;
    bf16* wqkv_h = (bf16*)(ws);              // 6 MB
    bf16* wqkv_l = (bf16*)(ws + 6 * MB);     // 6 MB
    bf16* wo_h   = (bf16*)(ws + 12 * MB);    // 2 MB
    bf16* wo_l   = (bf16*)(ws + 14 * MB);    // 2 MB (unused downstream)
    bf16* x_h    = (bf16*)(ws + 16 * MB);    // 8 MB
    bf16* x_l    = (bf16*)(ws + 24 * MB);    // 8 MB
    bf16* Q_h    = (bf16*)(ws + 32 * MB);    // 8 MB
    bf16* Q_l    = (bf16*)(ws + 40 * MB);    // 8 MB
    bf16* K_h    = (bf16*)(ws + 48 * MB);    // 8 MB
    bf16* K_l    = (bf16*)(ws + 56 * MB);    // 8 MB
    bf16* Vb     = (bf16*)(ws + 64 * MB);    // 8 MB
    bf16* Ob     = (bf16*)(ws);              // aliases wqkv (dead after QKV GEMM)

    split_x<<<dim3(2048), 256, 0, stream>>>(x, x_h, x_l);
    transpose_w<<<dim3(32, 32, 4), dim3(32, 8), 0, stream>>>(
        wq, wk, wv, wo, wqkv_h, wqkv_l, wo_h, wo_l);
    gemm_qkv3<<<dim3(32, 24), 256, 0, stream>>>(
        x_h, x_l, wqkv_h, wqkv_l, bq, bk, bv, Q_h, Q_l, K_h, K_l, Vb);
    attn_kernel<<<dim3(32, 32), 256, 0, stream>>>(Q_h, Q_l, K_h, K_l, Vb, Ob, alpha);
    gemm_out<<<dim3(32, 8), 256, 0, stream>>>(Ob, wo_h, bo, (float*)d_out);
}

// Round 4
// 340.670 us; speedup vs baseline: 1.2864x; 1.2864x over previous
//
#include <hip/hip_runtime.h>
#include <hip/hip_bf16.h>
#include <math.h>

typedef __bf16 bf16;
typedef bf16 bf16x4 __attribute__((ext_vector_type(4)));
typedef bf16 bf16x8 __attribute__((ext_vector_type(8)));
typedef float floatx4 __attribute__((ext_vector_type(4)));

#define MFMA16(a, b, c) __builtin_amdgcn_mfma_f32_16x16x32_bf16(a, b, c, 0, 0, 0)

__device__ __forceinline__ void split2(float v, bf16& h, bf16& l) {
    h = (bf16)v;
    l = (bf16)(v - (float)h);
}

// ---------------------------------------------------------------------------
// K0a: split x fp32 -> hi/lo bf16 (same layout)
// ---------------------------------------------------------------------------
__global__ void split_x(const float* __restrict__ x, bf16* __restrict__ xh,
                        bf16* __restrict__ xl) {
    const int i = (blockIdx.x * 256 + threadIdx.x) * 8;
    float4 a = *(const float4*)(x + i);
    float4 b = *(const float4*)(x + i + 4);
    bf16x8 oh, ol;
    float f[8] = {a.x, a.y, a.z, a.w, b.x, b.y, b.z, b.w};
#pragma unroll
    for (int j = 0; j < 8; j++) { bf16 h, l; split2(f[j], h, l); oh[j] = h; ol[j] = l; }
    *(bf16x8*)(xh + i) = oh;
    *(bf16x8*)(xl + i) = ol;
}

// ---------------------------------------------------------------------------
// K0b: transpose+split the 4 fp32 weights [1024][1024] W[k][n] -> hi/lo bf16 Wt[n][k]
// ---------------------------------------------------------------------------
__global__ void transpose_w(const float* __restrict__ wq, const float* __restrict__ wk,
                            const float* __restrict__ wv, const float* __restrict__ wo,
                            bf16* __restrict__ wt_qkv_h, bf16* __restrict__ wt_qkv_l,
                            bf16* __restrict__ wt_o_h) {
    const int z = blockIdx.z;
    const float* src = (z == 0) ? wq : (z == 1) ? wk : (z == 2) ? wv : wo;
    bf16* dsth = (z < 3) ? (wt_qkv_h + (size_t)z * 1024 * 1024) : wt_o_h;
    bf16* dstl = (z < 3) ? (wt_qkv_l + (size_t)z * 1024 * 1024) : nullptr;
    __shared__ float tile[32][33];
    const int x0 = blockIdx.x * 32, y0 = blockIdx.y * 32;
    const int tx = threadIdx.x, ty = threadIdx.y;  // (32,8)
    for (int i = 0; i < 32; i += 8)
        tile[ty + i][tx] = src[(size_t)(y0 + ty + i) * 1024 + x0 + tx];
    __syncthreads();
    for (int i = 0; i < 32; i += 8) {
        bf16 h, l;
        split2(tile[tx][ty + i], h, l);
        dsth[(size_t)(x0 + ty + i) * 1024 + y0 + tx] = h;
        if (dstl) dstl[(size_t)(x0 + ty + i) * 1024 + y0 + tx] = l;
    }
}

// ---------------------------------------------------------------------------
// K1: fused QKV GEMM, split-bf16: C = A * Bt^T + bias.  N=3072.
// Q,K slabs: 3-term (fp32-accurate), stored as hi/lo pairs [B,H,S,D].
// V slab: 1-term (bf16 accuracy suffices), stored TRANSPOSED as Vt[B,H,D,S].
// ---------------------------------------------------------------------------
__global__ __launch_bounds__(256, 2) void gemm_qkv3(
    const bf16* __restrict__ Ah, const bf16* __restrict__ Al,
    const bf16* __restrict__ Bth, const bf16* __restrict__ Btl,
    const float* __restrict__ bq, const float* __restrict__ bk,
    const float* __restrict__ bv,
    bf16* __restrict__ Qh, bf16* __restrict__ Ql,
    bf16* __restrict__ Kh, bf16* __restrict__ Kl, bf16* __restrict__ VtG) {
    __shared__ bf16 Ash[128 * 40];
    __shared__ bf16 Asl[128 * 40];
    __shared__ bf16 Bsh[128 * 40];
    __shared__ bf16 Bsl[128 * 40];

    const int t = threadIdx.x;
    const int lane = t & 63, wave = t >> 6;
    const int quad = lane >> 4, l16 = lane & 15;
    const int m0 = blockIdx.x * 128, n0 = blockIdx.y * 128;
    const int wm = (wave >> 1) * 64, wn = (wave & 1) * 64;
    const bool full = (n0 < 2048);  // Q/K slabs need the low-order terms

    const int srow = t >> 2;        // 0..63
    const int scol = (t & 3) * 8;   // 0/8/16/24
    const bf16* gAh = Ah + (size_t)(m0 + srow) * 1024 + scol;
    const bf16* gAl = Al + (size_t)(m0 + srow) * 1024 + scol;
    const bf16* gBh = Bth + (size_t)(n0 + srow) * 1024 + scol;
    const bf16* gBl = Btl + (size_t)(n0 + srow) * 1024 + scol;

    floatx4 acc[4][4] = {};

    for (int k0 = 0; k0 < 1024; k0 += 32) {
        bf16x8 rah0 = *(const bf16x8*)(gAh + k0);
        bf16x8 rah1 = *(const bf16x8*)(gAh + 64 * 1024 + k0);
        bf16x8 ral0 = *(const bf16x8*)(gAl + k0);
        bf16x8 ral1 = *(const bf16x8*)(gAl + 64 * 1024 + k0);
        bf16x8 rbh0 = *(const bf16x8*)(gBh + k0);
        bf16x8 rbh1 = *(const bf16x8*)(gBh + 64 * 1024 + k0);
        bf16x8 rbl0 = *(const bf16x8*)(gBl + k0);
        bf16x8 rbl1 = *(const bf16x8*)(gBl + 64 * 1024 + k0);
        __syncthreads();
        *(bf16x8*)&Ash[srow * 40 + scol] = rah0;
        *(bf16x8*)&Ash[(64 + srow) * 40 + scol] = rah1;
        *(bf16x8*)&Asl[srow * 40 + scol] = ral0;
        *(bf16x8*)&Asl[(64 + srow) * 40 + scol] = ral1;
        *(bf16x8*)&Bsh[srow * 40 + scol] = rbh0;
        *(bf16x8*)&Bsh[(64 + srow) * 40 + scol] = rbh1;
        *(bf16x8*)&Bsl[srow * 40 + scol] = rbl0;
        *(bf16x8*)&Bsl[(64 + srow) * 40 + scol] = rbl1;
        __syncthreads();
        bf16x8 afh[4], afl[4], bfh[4], bfl[4];
#pragma unroll
        for (int i = 0; i < 4; i++) {
            afh[i] = *(bf16x8*)&Ash[(wm + i * 16 + l16) * 40 + quad * 8];
            afl[i] = *(bf16x8*)&Asl[(wm + i * 16 + l16) * 40 + quad * 8];
        }
#pragma unroll
        for (int j = 0; j < 4; j++) {
            bfh[j] = *(bf16x8*)&Bsh[(wn + j * 16 + l16) * 40 + quad * 8];
            bfl[j] = *(bf16x8*)&Bsl[(wn + j * 16 + l16) * 40 + quad * 8];
        }
        if (full) {
#pragma unroll
            for (int i = 0; i < 4; i++)
#pragma unroll
                for (int j = 0; j < 4; j++) {
                    acc[i][j] = MFMA16(afh[i], bfh[j], acc[i][j]);
                    acc[i][j] = MFMA16(afh[i], bfl[j], acc[i][j]);
                    acc[i][j] = MFMA16(afl[i], bfh[j], acc[i][j]);
                }
        } else {
#pragma unroll
            for (int i = 0; i < 4; i++)
#pragma unroll
                for (int j = 0; j < 4; j++)
                    acc[i][j] = MFMA16(afh[i], bfh[j], acc[i][j]);
        }
    }

    const int which = n0 >> 10;  // 0=Q 1=K 2=V (128 | 1024, never straddles)
    const float* bias = (which == 0) ? bq : (which == 1) ? bk : bv;
#pragma unroll
    for (int i = 0; i < 4; i++)
#pragma unroll
        for (int j = 0; j < 4; j++) {
            const int col = n0 + wn + j * 16 + l16;
            const int o = col & 1023;
            const int h = o >> 6, d = o & 63;
            const float bvv = bias[o];
            const int gm0 = m0 + wm + i * 16 + quad * 4;  // token id of r=0
            const int b = gm0 >> 11;
            if (which == 2) {
                // V: store transposed Vt[b,h][d][s]; 4 consecutive s -> one 8B store
                bf16x4 pv;
#pragma unroll
                for (int r = 0; r < 4; r++) pv[r] = (bf16)(acc[i][j][r] + bvv);
                const int s0 = gm0 & 2047;
                *(bf16x4*)&VtG[((size_t)((b * 16 + h) * 64 + d)) * 2048 + s0] = pv;
            } else {
#pragma unroll
                for (int r = 0; r < 4; r++) {
                    const int gm = gm0 + r;
                    const int s = gm & 2047;
                    const size_t idx = (size_t)((b * 16 + h) * 2048 + s) * 64 + d;
                    const float val = acc[i][j][r] + bvv;
                    bf16 hi, lo;
                    split2(val, hi, lo);
                    if (which == 0) { Qh[idx] = hi; Ql[idx] = lo; }
                    else            { Kh[idx] = hi; Kl[idx] = lo; }
                }
            }
        }
}

// ---------------------------------------------------------------------------
// K2: flash attention, YAT scores, TRANSPOSED orientation:
//   S^T = K·Q^T (softmax row q = MFMA column l16 -> lane-local m/l state,
//   2-step shuffle reductions), O^T = V^T·P^T (V^T pre-transposed in global).
// Block: 256 thr = 4 waves; wave owns 16 q; block = 64 q; chunks of 64 keys.
// ---------------------------------------------------------------------------
__global__ __launch_bounds__(256, 2) void attn_kernel(
    const bf16* __restrict__ Qh, const bf16* __restrict__ Ql,
    const bf16* __restrict__ Kh, const bf16* __restrict__ Kl,
    const bf16* __restrict__ VtG, bf16* __restrict__ O,
    const float* __restrict__ alphap) {
    __shared__ bf16 Ksh[64 * 72];     // [key][d] hi
    __shared__ bf16 Ksl[64 * 72];     // [key][d] lo
    __shared__ bf16 Vs[64 * 72];      // [d][key] (vector-staged from global Vt)
    __shared__ bf16 Pt[4][64 * 20];   // per-wave P^T [key][q], stride 20 (conflict-free)
    __shared__ float kn_s[64];

    const int t = threadIdx.x, lane = t & 63, wave = t >> 6;
    const int quad = lane >> 4, l16 = lane & 15;
    const int bh = blockIdx.x;       // b*16+h
    const int q0 = blockIdx.y * 64;

    const size_t qbase = (size_t)(bh * 2048 + q0) * 64;
    const float alpha = alphap[0];
    const float sc = powf(8.0f / log1pf(64.0f), alpha);

    // Q^T B-fragments (hi+lo): B[k=d][n=q]: lane reads Q[q=l16][d=quad*8+j]
    const size_t qrow = qbase + (size_t)(wave * 16 + l16) * 64;
    const bf16x8 bq0h = *(const bf16x8*)(Qh + qrow + quad * 8);
    const bf16x8 bq1h = *(const bf16x8*)(Qh + qrow + 32 + quad * 8);
    const bf16x8 bq0l = *(const bf16x8*)(Ql + qrow + quad * 8);
    const bf16x8 bq1l = *(const bf16x8*)(Ql + qrow + 32 + quad * 8);

    // ||q||^2: lane-local partial (16 of 64 d) + quad reduction (xor 16,32)
    float qn = 0.f;
#pragma unroll
    for (int j = 0; j < 8; j++) {
        float x0 = (float)bq0h[j] + (float)bq0l[j];
        float x1 = (float)bq1h[j] + (float)bq1l[j];
        qn += x0 * x0 + x1 * x1;
    }
    qn += __shfl_xor(qn, 16, 64);
    qn += __shfl_xor(qn, 32, 64);
    const float qne = qn + 1e-5f;   // fold eps into q-norm

    floatx4 acco[4] = {};           // O^T: [dsub] rows d=dsub*16+quad*4+r, col q=l16
    float m_i = 0.f, l_i = 0.f;     // scores are always >= 0

    const int srow = t >> 3;        // 0..31
    const int scol = (t & 7) * 8;   // 0..56
    const size_t vrow0 = ((size_t)bh * 64 + srow) * 2048;
    const size_t vrow1 = ((size_t)bh * 64 + srow + 32) * 2048;

    for (int kc = 0; kc < 2048; kc += 64) {
        const size_t kbase = (size_t)(bh * 2048 + kc) * 64;
        // global loads up front (overlap with previous compute draining)
        bf16x8 kh0 = *(const bf16x8*)(Kh + kbase + srow * 64 + scol);
        bf16x8 kh1 = *(const bf16x8*)(Kh + kbase + (32 + srow) * 64 + scol);
        bf16x8 kl0 = *(const bf16x8*)(Kl + kbase + srow * 64 + scol);
        bf16x8 kl1 = *(const bf16x8*)(Kl + kbase + (32 + srow) * 64 + scol);
        bf16x8 v0 = *(const bf16x8*)(VtG + vrow0 + kc + scol);
        bf16x8 v1 = *(const bf16x8*)(VtG + vrow1 + kc + scol);
        // ||k||^2 partials from the registers we just loaded (8 of 64 d each)
        float p0 = 0.f, p1 = 0.f;
#pragma unroll
        for (int j = 0; j < 8; j++) {
            float x0 = (float)kh0[j] + (float)kl0[j];
            float x1 = (float)kh1[j] + (float)kl1[j];
            p0 += x0 * x0;
            p1 += x1 * x1;
        }
        p0 += __shfl_xor(p0, 1, 64); p0 += __shfl_xor(p0, 2, 64); p0 += __shfl_xor(p0, 4, 64);
        p1 += __shfl_xor(p1, 1, 64); p1 += __shfl_xor(p1, 2, 64); p1 += __shfl_xor(p1, 4, 64);
        __syncthreads();  // previous chunk's LDS reads complete
        *(bf16x8*)&Ksh[srow * 72 + scol] = kh0;
        *(bf16x8*)&Ksh[(32 + srow) * 72 + scol] = kh1;
        *(bf16x8*)&Ksl[srow * 72 + scol] = kl0;
        *(bf16x8*)&Ksl[(32 + srow) * 72 + scol] = kl1;
        *(bf16x8*)&Vs[srow * 72 + scol] = v0;
        *(bf16x8*)&Vs[(32 + srow) * 72 + scol] = v1;
        if ((t & 7) == 0) { kn_s[srow] = p0; kn_s[srow + 32] = p1; }
        __syncthreads();

        // S^T = K·Q^T (split 3-term) -> YAT scores
        // lane holds 16 scores: key = sub*16+quad*4+r, q = l16
        float pbuf[4][4];
        float mloc = 0.f;
#pragma unroll
        for (int sub = 0; sub < 4; sub++) {
            floatx4 accs = {};
            bf16x8 a0h = *(bf16x8*)&Ksh[(sub * 16 + l16) * 72 + quad * 8];
            bf16x8 a1h = *(bf16x8*)&Ksh[(sub * 16 + l16) * 72 + 32 + quad * 8];
            bf16x8 a0l = *(bf16x8*)&Ksl[(sub * 16 + l16) * 72 + quad * 8];
            bf16x8 a1l = *(bf16x8*)&Ksl[(sub * 16 + l16) * 72 + 32 + quad * 8];
            accs = MFMA16(a0h, bq0h, accs);
            accs = MFMA16(a1h, bq1h, accs);
            accs = MFMA16(a0h, bq0l, accs);
            accs = MFMA16(a1h, bq1l, accs);
            accs = MFMA16(a0l, bq0h, accs);
            accs = MFMA16(a1l, bq1h, accs);
#pragma unroll
            for (int r = 0; r < 4; r++) {
                const float dot = accs[r];
                const float kn = kn_s[sub * 16 + quad * 4 + r];  // LDS broadcast
                const float d2 = qne + kn - 2.0f * dot;
                const float s = sc * dot * dot * __builtin_amdgcn_rcpf(d2);
                pbuf[sub][r] = s;
                mloc = fmaxf(mloc, s);
            }
        }
        // online softmax for column q=l16: reduce over quads only
        mloc = fmaxf(mloc, __shfl_xor(mloc, 16, 64));
        mloc = fmaxf(mloc, __shfl_xor(mloc, 32, 64));
        const float mnew = fmaxf(m_i, mloc);
        const float al = __expf(m_i - mnew);
        float rs = 0.f;
        bf16* Pw = Pt[wave];
#pragma unroll
        for (int sub = 0; sub < 4; sub++)
#pragma unroll
            for (int r = 0; r < 4; r++) {
                const float p = __expf(pbuf[sub][r] - mnew);
                rs += p;
                Pw[(sub * 16 + quad * 4 + r) * 20 + l16] = (bf16)p;
            }
        rs += __shfl_xor(rs, 16, 64);
        rs += __shfl_xor(rs, 32, 64);
        l_i = l_i * al + rs;
        m_i = mnew;
#pragma unroll
        for (int dsub = 0; dsub < 4; dsub++) acco[dsub] *= al;

        // O^T += V^T·P^T  (same-wave Pt round-trip; compiler orders via lgkmcnt)
        bf16x8 bp0, bp1;  // B[k=key][n=q]: column q=l16 of Pt, 8 key-rows each
#pragma unroll
        for (int j = 0; j < 8; j++) {
            bp0[j] = Pw[(quad * 8 + j) * 20 + l16];
            bp1[j] = Pw[(32 + quad * 8 + j) * 20 + l16];
        }
#pragma unroll
        for (int dsub = 0; dsub < 4; dsub++) {
            bf16x8 a0 = *(bf16x8*)&Vs[(dsub * 16 + l16) * 72 + quad * 8];
            bf16x8 a1 = *(bf16x8*)&Vs[(dsub * 16 + l16) * 72 + 32 + quad * 8];
            acco[dsub] = MFMA16(a0, bp0, acco[dsub]);
            acco[dsub] = MFMA16(a1, bp1, acco[dsub]);
        }
    }

    // epilogue: O[b][s][h*64+d]; lane's 4 r-values are d-contiguous -> 8B stores
    const int b = bh >> 4, h = bh & 15;
    const int s = q0 + wave * 16 + l16;
    const float rl = 1.0f / l_i;
    float* obase_f;  // silence unused warnings pattern; direct address below
    (void)obase_f;
    const size_t obase = (size_t)(b * 2048 + s) * 1024 + h * 64;
#pragma unroll
    for (int dsub = 0; dsub < 4; dsub++) {
        bf16x4 ov;
#pragma unroll
        for (int r = 0; r < 4; r++) ov[r] = (bf16)(acco[dsub][r] * rl);
        *(bf16x4*)&O[obase + dsub * 16 + quad * 4] = ov;
    }
}

// ---------------------------------------------------------------------------
// K3: out-proj GEMM (single bf16 pass), fp32 output: out = Ob * wt_o^T + bo
// ---------------------------------------------------------------------------
__global__ __launch_bounds__(256, 2) void gemm_out(
    const bf16* __restrict__ A, const bf16* __restrict__ Bt,
    const float* __restrict__ bias, float* __restrict__ outC) {
    __shared__ bf16 As[128 * 40];
    __shared__ bf16 Bs[128 * 40];

    const int t = threadIdx.x;
    const int lane = t & 63, wave = t >> 6;
    const int quad = lane >> 4, l16 = lane & 15;
    const int m0 = blockIdx.x * 128, n0 = blockIdx.y * 128;
    const int wm = (wave >> 1) * 64, wn = (wave & 1) * 64;

    const int srow = t >> 2;
    const int scol = (t & 3) * 8;
    const bf16* gA0 = A + (size_t)(m0 + srow) * 1024 + scol;
    const bf16* gB0 = Bt + (size_t)(n0 + srow) * 1024 + scol;

    floatx4 acc[4][4] = {};

    for (int k0 = 0; k0 < 1024; k0 += 32) {
        bf16x8 ra0 = *(const bf16x8*)(gA0 + k0);
        bf16x8 ra1 = *(const bf16x8*)(gA0 + 64 * 1024 + k0);
        bf16x8 rb0 = *(const bf16x8*)(gB0 + k0);
        bf16x8 rb1 = *(const bf16x8*)(gB0 + 64 * 1024 + k0);
        __syncthreads();
        *(bf16x8*)&As[srow * 40 + scol] = ra0;
        *(bf16x8*)&As[(64 + srow) * 40 + scol] = ra1;
        *(bf16x8*)&Bs[srow * 40 + scol] = rb0;
        *(bf16x8*)&Bs[(64 + srow) * 40 + scol] = rb1;
        __syncthreads();
        bf16x8 af[4], bf_[4];
#pragma unroll
        for (int i = 0; i < 4; i++)
            af[i] = *(bf16x8*)&As[(wm + i * 16 + l16) * 40 + quad * 8];
#pragma unroll
        for (int j = 0; j < 4; j++)
            bf_[j] = *(bf16x8*)&Bs[(wn + j * 16 + l16) * 40 + quad * 8];
#pragma unroll
        for (int i = 0; i < 4; i++)
#pragma unroll
            for (int j = 0; j < 4; j++)
                acc[i][j] = MFMA16(af[i], bf_[j], acc[i][j]);
    }

#pragma unroll
    for (int i = 0; i < 4; i++)
#pragma unroll
        for (int j = 0; j < 4; j++) {
            const int col = n0 + wn + j * 16 + l16;
            const float bvv = bias[col];
#pragma unroll
            for (int r = 0; r < 4; r++) {
                const int gm = m0 + wm + i * 16 + quad * 4 + r;
                outC[(size_t)gm * 1024 + col] = acc[i][j][r] + bvv;
            }
        }
}

// ---------------------------------------------------------------------------
extern "C" void kernel_launch(void* const* d_in, const int* in_sizes, int n_in,
                              void* d_out, int out_size, void* d_ws, size_t ws_size,
                              hipStream_t stream) {
    const float* x  = (const float*)d_in[0];
    const float* wq = (const float*)d_in[1];
    const float* bq = (const float*)d_in[2];
    const float* wk = (const float*)d_in[3];
    const float* bk = (const float*)d_in[4];
    const float* wv = (const float*)d_in[5];
    const float* bv = (const float*)d_in[6];
    const float* wo = (const float*)d_in[7];
    const float* bo = (const float*)d_in[8];
    const float* alpha = (const float*)d_in[9];

    char* ws = (char*)d_ws;
    const size_t MB = 1024 * 1024;
    bf16* wqkv_h = (bf16*)(ws);              // 6 MB
    bf16* wqkv_l = (bf16*)(ws + 6 * MB);     // 6 MB
    bf16* wo_h   = (bf16*)(ws + 12 * MB);    // 2 MB
    bf16* x_h    = (bf16*)(ws + 16 * MB);    // 8 MB
    bf16* x_l    = (bf16*)(ws + 24 * MB);    // 8 MB
    bf16* Q_h    = (bf16*)(ws + 32 * MB);    // 8 MB
    bf16* Q_l    = (bf16*)(ws + 40 * MB);    // 8 MB
    bf16* K_h    = (bf16*)(ws + 48 * MB);    // 8 MB
    bf16* K_l    = (bf16*)(ws + 56 * MB);    // 8 MB
    bf16* Vt_g   = (bf16*)(ws + 64 * MB);    // 8 MB, [B,H,D,S]
    bf16* Ob     = (bf16*)(ws);              // aliases wqkv (dead after QKV GEMM)

    split_x<<<dim3(2048), 256, 0, stream>>>(x, x_h, x_l);
    transpose_w<<<dim3(32, 32, 4), dim3(32, 8), 0, stream>>>(
        wq, wk, wv, wo, wqkv_h, wqkv_l, wo_h);
    gemm_qkv3<<<dim3(32, 24), 256, 0, stream>>>(
        x_h, x_l, wqkv_h, wqkv_l, bq, bk, bv, Q_h, Q_l, K_h, K_l, Vt_g);
    attn_kernel<<<dim3(32, 32), 256, 0, stream>>>(Q_h, Q_l, K_h, K_l, Vt_g, Ob, alpha);
    gemm_out<<<dim3(32, 8), 256, 0, stream>>>(Ob, wo_h, bo, (float*)d_out);
}

// Round 5
// 301.087 us; speedup vs baseline: 1.4555x; 1.1315x over previous
//
#include <hip/hip_runtime.h>
#include <hip/hip_bf16.h>
#include <math.h>

typedef __bf16 bf16;
typedef bf16 bf16x4 __attribute__((ext_vector_type(4)));
typedef bf16 bf16x8 __attribute__((ext_vector_type(8)));
typedef float floatx4 __attribute__((ext_vector_type(4)));

#define MFMA16(a, b, c) __builtin_amdgcn_mfma_f32_16x16x32_bf16(a, b, c, 0, 0, 0)

__device__ __forceinline__ void split2(float v, bf16& h, bf16& l) {
    h = (bf16)v;
    l = (bf16)(v - (float)h);
}

// ---------------------------------------------------------------------------
// K0a: split x fp32 -> hi/lo bf16 (same layout)
// ---------------------------------------------------------------------------
__global__ void split_x(const float* __restrict__ x, bf16* __restrict__ xh,
                        bf16* __restrict__ xl) {
    const int i = (blockIdx.x * 256 + threadIdx.x) * 8;
    float4 a = *(const float4*)(x + i);
    float4 b = *(const float4*)(x + i + 4);
    bf16x8 oh, ol;
    float f[8] = {a.x, a.y, a.z, a.w, b.x, b.y, b.z, b.w};
#pragma unroll
    for (int j = 0; j < 8; j++) { bf16 h, l; split2(f[j], h, l); oh[j] = h; ol[j] = l; }
    *(bf16x8*)(xh + i) = oh;
    *(bf16x8*)(xl + i) = ol;
}

// ---------------------------------------------------------------------------
// K0b: transpose+split the 4 fp32 weights [1024][1024] W[k][n] -> hi/lo bf16 Wt[n][k]
// ---------------------------------------------------------------------------
__global__ void transpose_w(const float* __restrict__ wq, const float* __restrict__ wk,
                            const float* __restrict__ wv, const float* __restrict__ wo,
                            bf16* __restrict__ wt_qkv_h, bf16* __restrict__ wt_qkv_l,
                            bf16* __restrict__ wt_o_h) {
    const int z = blockIdx.z;
    const float* src = (z == 0) ? wq : (z == 1) ? wk : (z == 2) ? wv : wo;
    bf16* dsth = (z < 3) ? (wt_qkv_h + (size_t)z * 1024 * 1024) : wt_o_h;
    bf16* dstl = (z < 3) ? (wt_qkv_l + (size_t)z * 1024 * 1024) : nullptr;
    __shared__ float tile[32][33];
    const int x0 = blockIdx.x * 32, y0 = blockIdx.y * 32;
    const int tx = threadIdx.x, ty = threadIdx.y;  // (32,8)
    for (int i = 0; i < 32; i += 8)
        tile[ty + i][tx] = src[(size_t)(y0 + ty + i) * 1024 + x0 + tx];
    __syncthreads();
    for (int i = 0; i < 32; i += 8) {
        bf16 h, l;
        split2(tile[tx][ty + i], h, l);
        dsth[(size_t)(x0 + ty + i) * 1024 + y0 + tx] = h;
        if (dstl) dstl[(size_t)(x0 + ty + i) * 1024 + y0 + tx] = l;
    }
}

// ---------------------------------------------------------------------------
// K1: fused QKV GEMM, split-bf16: C = A * Bt^T + bias.  N=3072.
// Q,K slabs: 3-term (fp32-accurate), stored as hi/lo pairs [B,H,S,D].
// V slab: 1-term (bf16 suffices), stored TRANSPOSED as Vt[B,H,D,S].
// ---------------------------------------------------------------------------
__global__ __launch_bounds__(256, 2) void gemm_qkv3(
    const bf16* __restrict__ Ah, const bf16* __restrict__ Al,
    const bf16* __restrict__ Bth, const bf16* __restrict__ Btl,
    const float* __restrict__ bq, const float* __restrict__ bk,
    const float* __restrict__ bv,
    bf16* __restrict__ Qh, bf16* __restrict__ Ql,
    bf16* __restrict__ Kh, bf16* __restrict__ Kl, bf16* __restrict__ VtG) {
    __shared__ bf16 Ash[128 * 40];
    __shared__ bf16 Asl[128 * 40];
    __shared__ bf16 Bsh[128 * 40];
    __shared__ bf16 Bsl[128 * 40];

    const int t = threadIdx.x;
    const int lane = t & 63, wave = t >> 6;
    const int quad = lane >> 4, l16 = lane & 15;
    const int m0 = blockIdx.x * 128, n0 = blockIdx.y * 128;
    const int wm = (wave >> 1) * 64, wn = (wave & 1) * 64;
    const bool full = (n0 < 2048);  // Q/K slabs need the low-order terms

    const int srow = t >> 2;        // 0..63
    const int scol = (t & 3) * 8;   // 0/8/16/24
    const bf16* gAh = Ah + (size_t)(m0 + srow) * 1024 + scol;
    const bf16* gAl = Al + (size_t)(m0 + srow) * 1024 + scol;
    const bf16* gBh = Bth + (size_t)(n0 + srow) * 1024 + scol;
    const bf16* gBl = Btl + (size_t)(n0 + srow) * 1024 + scol;

    floatx4 acc[4][4] = {};

    for (int k0 = 0; k0 < 1024; k0 += 32) {
        bf16x8 rah0 = *(const bf16x8*)(gAh + k0);
        bf16x8 rah1 = *(const bf16x8*)(gAh + 64 * 1024 + k0);
        bf16x8 rbh0 = *(const bf16x8*)(gBh + k0);
        bf16x8 rbh1 = *(const bf16x8*)(gBh + 64 * 1024 + k0);
        bf16x8 ral0, ral1, rbl0, rbl1;
        if (full) {
            ral0 = *(const bf16x8*)(gAl + k0);
            ral1 = *(const bf16x8*)(gAl + 64 * 1024 + k0);
            rbl0 = *(const bf16x8*)(gBl + k0);
            rbl1 = *(const bf16x8*)(gBl + 64 * 1024 + k0);
        }
        __syncthreads();
        *(bf16x8*)&Ash[srow * 40 + scol] = rah0;
        *(bf16x8*)&Ash[(64 + srow) * 40 + scol] = rah1;
        *(bf16x8*)&Bsh[srow * 40 + scol] = rbh0;
        *(bf16x8*)&Bsh[(64 + srow) * 40 + scol] = rbh1;
        if (full) {
            *(bf16x8*)&Asl[srow * 40 + scol] = ral0;
            *(bf16x8*)&Asl[(64 + srow) * 40 + scol] = ral1;
            *(bf16x8*)&Bsl[srow * 40 + scol] = rbl0;
            *(bf16x8*)&Bsl[(64 + srow) * 40 + scol] = rbl1;
        }
        __syncthreads();
        bf16x8 afh[4], bfh[4];
#pragma unroll
        for (int i = 0; i < 4; i++)
            afh[i] = *(bf16x8*)&Ash[(wm + i * 16 + l16) * 40 + quad * 8];
#pragma unroll
        for (int j = 0; j < 4; j++)
            bfh[j] = *(bf16x8*)&Bsh[(wn + j * 16 + l16) * 40 + quad * 8];
        if (full) {
            bf16x8 afl[4], bfl[4];
#pragma unroll
            for (int i = 0; i < 4; i++)
                afl[i] = *(bf16x8*)&Asl[(wm + i * 16 + l16) * 40 + quad * 8];
#pragma unroll
            for (int j = 0; j < 4; j++)
                bfl[j] = *(bf16x8*)&Bsl[(wn + j * 16 + l16) * 40 + quad * 8];
#pragma unroll
            for (int i = 0; i < 4; i++)
#pragma unroll
                for (int j = 0; j < 4; j++) {
                    acc[i][j] = MFMA16(afh[i], bfh[j], acc[i][j]);
                    acc[i][j] = MFMA16(afh[i], bfl[j], acc[i][j]);
                    acc[i][j] = MFMA16(afl[i], bfh[j], acc[i][j]);
                }
        } else {
#pragma unroll
            for (int i = 0; i < 4; i++)
#pragma unroll
                for (int j = 0; j < 4; j++)
                    acc[i][j] = MFMA16(afh[i], bfh[j], acc[i][j]);
        }
    }

    const int which = n0 >> 10;  // 0=Q 1=K 2=V (128 | 1024, never straddles)
    const float* bias = (which == 0) ? bq : (which == 1) ? bk : bv;
#pragma unroll
    for (int i = 0; i < 4; i++)
#pragma unroll
        for (int j = 0; j < 4; j++) {
            const int col = n0 + wn + j * 16 + l16;
            const int o = col & 1023;
            const int h = o >> 6, d = o & 63;
            const float bvv = bias[o];
            const int gm0 = m0 + wm + i * 16 + quad * 4;  // token id of r=0
            const int b = gm0 >> 11;
            if (which == 2) {
                bf16x4 pv;
#pragma unroll
                for (int r = 0; r < 4; r++) pv[r] = (bf16)(acc[i][j][r] + bvv);
                const int s0 = gm0 & 2047;
                *(bf16x4*)&VtG[((size_t)((b * 16 + h) * 64 + d)) * 2048 + s0] = pv;
            } else {
#pragma unroll
                for (int r = 0; r < 4; r++) {
                    const int gm = gm0 + r;
                    const int s = gm & 2047;
                    const size_t idx = (size_t)((b * 16 + h) * 2048 + s) * 64 + d;
                    const float val = acc[i][j][r] + bvv;
                    bf16 hi, lo;
                    split2(val, hi, lo);
                    if (which == 0) { Qh[idx] = hi; Ql[idx] = lo; }
                    else            { Kh[idx] = hi; Kl[idx] = lo; }
                }
            }
        }
}

// ---------------------------------------------------------------------------
// K1b: precompute ||k||^2 per key row (fp32 from hi+lo), knG[bh*2048+s]
// ---------------------------------------------------------------------------
__global__ void kn_kernel(const bf16* __restrict__ Kh, const bf16* __restrict__ Kl,
                          float* __restrict__ knG) {
    const int i = blockIdx.x * 256 + threadIdx.x;  // 0..65535
    const bf16* ph = Kh + (size_t)i * 64;
    const bf16* pl = Kl + (size_t)i * 64;
    float s = 0.f;
#pragma unroll
    for (int d0 = 0; d0 < 64; d0 += 8) {
        bf16x8 vh = *(const bf16x8*)(ph + d0);
        bf16x8 vl = *(const bf16x8*)(pl + d0);
#pragma unroll
        for (int j = 0; j < 8; j++) { float x = (float)vh[j] + (float)vl[j]; s += x * x; }
    }
    knG[i] = s;
}

// ---------------------------------------------------------------------------
// K2: flash attention, YAT scores, transposed orientation, 32 q per wave.
//   S^T = K·Q^T (3-term split), online softmax per q-column (lane-local),
//   O^T = V^T·P^T.  Block = 4 waves = 128 q; chunks of 64 keys.
// ---------------------------------------------------------------------------
__global__ __launch_bounds__(256, 2) void attn_kernel(
    const bf16* __restrict__ Qh, const bf16* __restrict__ Ql,
    const bf16* __restrict__ Kh, const bf16* __restrict__ Kl,
    const bf16* __restrict__ VtG, const float* __restrict__ knG,
    bf16* __restrict__ O, const float* __restrict__ alphap) {
    __shared__ bf16 Ksh[64 * 72];     // [key][d] hi
    __shared__ bf16 Ksl[64 * 72];     // [key][d] lo
    __shared__ bf16 Vs[64 * 72];      // [d][key]
    __shared__ bf16 Pt[4][32 * 72];   // per-wave P [q][key], stride 72
    __shared__ float knL[64];

    const int t = threadIdx.x, lane = t & 63, wave = t >> 6;
    const int quad = lane >> 4, l16 = lane & 15;
    const int bh = blockIdx.x;        // b*16+h
    const int qw = blockIdx.y * 128 + wave * 32;  // wave's first q

    const float alpha = alphap[0];
    // fold sc and log2(e) into the score so softmax uses raw exp2
    const float C = powf(8.0f / log1pf(64.0f), alpha) * 1.44269504f;

    // Q^T B-fragments (hi+lo), 2 q-groups of 16: B[k=d][n=q]
    const size_t qrow0 = ((size_t)bh * 2048 + qw + l16) * 64;
    const size_t qrow1 = qrow0 + 16 * 64;
    bf16x8 bq0h[2], bq1h[2], bq0l[2], bq1l[2];
    bq0h[0] = *(const bf16x8*)(Qh + qrow0 + quad * 8);
    bq1h[0] = *(const bf16x8*)(Qh + qrow0 + 32 + quad * 8);
    bq0l[0] = *(const bf16x8*)(Ql + qrow0 + quad * 8);
    bq1l[0] = *(const bf16x8*)(Ql + qrow0 + 32 + quad * 8);
    bq0h[1] = *(const bf16x8*)(Qh + qrow1 + quad * 8);
    bq1h[1] = *(const bf16x8*)(Qh + qrow1 + 32 + quad * 8);
    bq0l[1] = *(const bf16x8*)(Ql + qrow1 + quad * 8);
    bq1l[1] = *(const bf16x8*)(Ql + qrow1 + 32 + quad * 8);

    // ||q||^2 per q-group (lane-local 16 d + quad reduce), eps folded in
    float qne[2];
#pragma unroll
    for (int qg = 0; qg < 2; qg++) {
        float qn = 0.f;
#pragma unroll
        for (int j = 0; j < 8; j++) {
            float x0 = (float)bq0h[qg][j] + (float)bq0l[qg][j];
            float x1 = (float)bq1h[qg][j] + (float)bq1l[qg][j];
            qn += x0 * x0 + x1 * x1;
        }
        qn += __shfl_xor(qn, 16, 64);
        qn += __shfl_xor(qn, 32, 64);
        qne[qg] = qn + 1e-5f;
    }

    floatx4 acco[2][4] = {};          // O^T per qg: row d=dsub*16+quad*4+r, col q=l16
    float m_i[2] = {0.f, 0.f};        // scores >= 0 (exp2 domain)
    float l_i[2] = {0.f, 0.f};

    const int srow = t >> 3;          // 0..31
    const int scol = (t & 7) * 8;     // 0..56
    const size_t vrow0 = ((size_t)bh * 64 + srow) * 2048;
    const size_t vrow1 = ((size_t)bh * 64 + srow + 32) * 2048;
    const float* knB = knG + (size_t)bh * 2048;

    for (int kc = 0; kc < 2048; kc += 64) {
        const size_t kbase = (size_t)(bh * 2048 + kc) * 64;
        bf16x8 kh0 = *(const bf16x8*)(Kh + kbase + srow * 64 + scol);
        bf16x8 kh1 = *(const bf16x8*)(Kh + kbase + (32 + srow) * 64 + scol);
        bf16x8 kl0 = *(const bf16x8*)(Kl + kbase + srow * 64 + scol);
        bf16x8 kl1 = *(const bf16x8*)(Kl + kbase + (32 + srow) * 64 + scol);
        bf16x8 v0 = *(const bf16x8*)(VtG + vrow0 + kc + scol);
        bf16x8 v1 = *(const bf16x8*)(VtG + vrow1 + kc + scol);
        __syncthreads();  // previous chunk's LDS reads complete
        *(bf16x8*)&Ksh[srow * 72 + scol] = kh0;
        *(bf16x8*)&Ksh[(32 + srow) * 72 + scol] = kh1;
        *(bf16x8*)&Ksl[srow * 72 + scol] = kl0;
        *(bf16x8*)&Ksl[(32 + srow) * 72 + scol] = kl1;
        *(bf16x8*)&Vs[srow * 72 + scol] = v0;
        *(bf16x8*)&Vs[(32 + srow) * 72 + scol] = v1;
        if (t < 16) *(float4*)&knL[t * 4] = *(const float4*)(knB + kc + t * 4);
        __syncthreads();

        // S^T = K·Q^T (split 3-term) -> YAT scores (exp2-scaled)
        float pbuf[2][4][4];
        float mloc[2] = {0.f, 0.f};
#pragma unroll
        for (int sub = 0; sub < 4; sub++) {
            bf16x8 a0h = *(bf16x8*)&Ksh[(sub * 16 + l16) * 72 + quad * 8];
            bf16x8 a1h = *(bf16x8*)&Ksh[(sub * 16 + l16) * 72 + 32 + quad * 8];
            bf16x8 a0l = *(bf16x8*)&Ksl[(sub * 16 + l16) * 72 + quad * 8];
            bf16x8 a1l = *(bf16x8*)&Ksl[(sub * 16 + l16) * 72 + 32 + quad * 8];
            floatx4 ac0 = {}, ac1 = {};
            ac0 = MFMA16(a0h, bq0h[0], ac0);
            ac0 = MFMA16(a1h, bq1h[0], ac0);
            ac0 = MFMA16(a0h, bq0l[0], ac0);
            ac0 = MFMA16(a1h, bq1l[0], ac0);
            ac0 = MFMA16(a0l, bq0h[0], ac0);
            ac0 = MFMA16(a1l, bq1h[0], ac0);
            ac1 = MFMA16(a0h, bq0h[1], ac1);
            ac1 = MFMA16(a1h, bq1h[1], ac1);
            ac1 = MFMA16(a0h, bq0l[1], ac1);
            ac1 = MFMA16(a1h, bq1l[1], ac1);
            ac1 = MFMA16(a0l, bq0h[1], ac1);
            ac1 = MFMA16(a1l, bq1h[1], ac1);
            const floatx4 knv = *(const floatx4*)&knL[sub * 16 + quad * 4];
#pragma unroll
            for (int r = 0; r < 4; r++) {
                const float d0 = ac0[r];
                const float d1 = ac1[r];
                const float e0 = fmaf(-2.0f, d0, qne[0] + knv[r]);
                const float e1 = fmaf(-2.0f, d1, qne[1] + knv[r]);
                const float s0 = C * d0 * d0 * __builtin_amdgcn_rcpf(e0);
                const float s1 = C * d1 * d1 * __builtin_amdgcn_rcpf(e1);
                pbuf[0][sub][r] = s0;
                pbuf[1][sub][r] = s1;
                mloc[0] = fmaxf(mloc[0], s0);
                mloc[1] = fmaxf(mloc[1], s1);
            }
        }

        // online softmax per q-column + P writes (b64, [q][key])
        bf16* Pw = Pt[wave];
#pragma unroll
        for (int qg = 0; qg < 2; qg++) {
            float mx = mloc[qg];
            mx = fmaxf(mx, __shfl_xor(mx, 16, 64));
            mx = fmaxf(mx, __shfl_xor(mx, 32, 64));
            const float mnew = fmaxf(m_i[qg], mx);
            const float al = __builtin_amdgcn_exp2f(m_i[qg] - mnew);
            float rs = 0.f;
            bf16* Pq = Pw + (qg * 16 + l16) * 72;
#pragma unroll
            for (int sub = 0; sub < 4; sub++) {
                bf16x4 pv;
#pragma unroll
                for (int r = 0; r < 4; r++) {
                    const float p = __builtin_amdgcn_exp2f(pbuf[qg][sub][r] - mnew);
                    rs += p;
                    pv[r] = (bf16)p;
                }
                *(bf16x4*)&Pq[sub * 16 + quad * 4] = pv;
            }
            rs += __shfl_xor(rs, 16, 64);
            rs += __shfl_xor(rs, 32, 64);
            l_i[qg] = l_i[qg] * al + rs;
            m_i[qg] = mnew;
#pragma unroll
            for (int dsub = 0; dsub < 4; dsub++) acco[qg][dsub] *= al;
        }

        // O^T += V^T·P^T (same-wave Pt round-trip; b128 B-frag reads)
        bf16x8 bp0[2], bp1[2];
#pragma unroll
        for (int qg = 0; qg < 2; qg++) {
            bp0[qg] = *(bf16x8*)&Pw[(qg * 16 + l16) * 72 + quad * 8];
            bp1[qg] = *(bf16x8*)&Pw[(qg * 16 + l16) * 72 + 32 + quad * 8];
        }
#pragma unroll
        for (int dsub = 0; dsub < 4; dsub++) {
            bf16x8 a0 = *(bf16x8*)&Vs[(dsub * 16 + l16) * 72 + quad * 8];
            bf16x8 a1 = *(bf16x8*)&Vs[(dsub * 16 + l16) * 72 + 32 + quad * 8];
            acco[0][dsub] = MFMA16(a0, bp0[0], acco[0][dsub]);
            acco[0][dsub] = MFMA16(a1, bp1[0], acco[0][dsub]);
            acco[1][dsub] = MFMA16(a0, bp0[1], acco[1][dsub]);
            acco[1][dsub] = MFMA16(a1, bp1[1], acco[1][dsub]);
        }
    }

    // epilogue: O[b][s][h*64+d]; 4 r-values are d-contiguous -> b64 stores
    const int b = bh >> 4, h = bh & 15;
#pragma unroll
    for (int qg = 0; qg < 2; qg++) {
        const int s = qw + qg * 16 + l16;
        const float rl = 1.0f / l_i[qg];
        const size_t obase = (size_t)(b * 2048 + s) * 1024 + h * 64;
#pragma unroll
        for (int dsub = 0; dsub < 4; dsub++) {
            bf16x4 ov;
#pragma unroll
            for (int r = 0; r < 4; r++) ov[r] = (bf16)(acco[qg][dsub][r] * rl);
            *(bf16x4*)&O[obase + dsub * 16 + quad * 4] = ov;
        }
    }
}

// ---------------------------------------------------------------------------
// K3: out-proj GEMM (single bf16 pass), fp32 output: out = Ob * wt_o^T + bo
// ---------------------------------------------------------------------------
__global__ __launch_bounds__(256, 2) void gemm_out(
    const bf16* __restrict__ A, const bf16* __restrict__ Bt,
    const float* __restrict__ bias, float* __restrict__ outC) {
    __shared__ bf16 As[128 * 40];
    __shared__ bf16 Bs[128 * 40];

    const int t = threadIdx.x;
    const int lane = t & 63, wave = t >> 6;
    const int quad = lane >> 4, l16 = lane & 15;
    const int m0 = blockIdx.x * 128, n0 = blockIdx.y * 128;
    const int wm = (wave >> 1) * 64, wn = (wave & 1) * 64;

    const int srow = t >> 2;
    const int scol = (t & 3) * 8;
    const bf16* gA0 = A + (size_t)(m0 + srow) * 1024 + scol;
    const bf16* gB0 = Bt + (size_t)(n0 + srow) * 1024 + scol;

    floatx4 acc[4][4] = {};

    for (int k0 = 0; k0 < 1024; k0 += 32) {
        bf16x8 ra0 = *(const bf16x8*)(gA0 + k0);
        bf16x8 ra1 = *(const bf16x8*)(gA0 + 64 * 1024 + k0);
        bf16x8 rb0 = *(const bf16x8*)(gB0 + k0);
        bf16x8 rb1 = *(const bf16x8*)(gB0 + 64 * 1024 + k0);
        __syncthreads();
        *(bf16x8*)&As[srow * 40 + scol] = ra0;
        *(bf16x8*)&As[(64 + srow) * 40 + scol] = ra1;
        *(bf16x8*)&Bs[srow * 40 + scol] = rb0;
        *(bf16x8*)&Bs[(64 + srow) * 40 + scol] = rb1;
        __syncthreads();
        bf16x8 af[4], bf_[4];
#pragma unroll
        for (int i = 0; i < 4; i++)
            af[i] = *(bf16x8*)&As[(wm + i * 16 + l16) * 40 + quad * 8];
#pragma unroll
        for (int j = 0; j < 4; j++)
            bf_[j] = *(bf16x8*)&Bs[(wn + j * 16 + l16) * 40 + quad * 8];
#pragma unroll
        for (int i = 0; i < 4; i++)
#pragma unroll
            for (int j = 0; j < 4; j++)
                acc[i][j] = MFMA16(af[i], bf_[j], acc[i][j]);
    }

#pragma unroll
    for (int i = 0; i < 4; i++)
#pragma unroll
        for (int j = 0; j < 4; j++) {
            const int col = n0 + wn + j * 16 + l16;
            const float bvv = bias[col];
#pragma unroll
            for (int r = 0; r < 4; r++) {
                const int gm = m0 + wm + i * 16 + quad * 4 + r;
                outC[(size_t)gm * 1024 + col] = acc[i][j][r] + bvv;
            }
        }
}

// ---------------------------------------------------------------------------
extern "C" void kernel_launch(void* const* d_in, const int* in_sizes, int n_in,
                              void* d_out, int out_size, void* d_ws, size_t ws_size,
                              hipStream_t stream) {
    const float* x  = (const float*)d_in[0];
    const float* wq = (const float*)d_in[1];
    const float* bq = (const float*)d_in[2];
    const float* wk = (const float*)d_in[3];
    const float* bk = (const float*)d_in[4];
    const float* wv = (const float*)d_in[5];
    const float* bv = (const float*)d_in[6];
    const float* wo = (const float*)d_in[7];
    const float* bo = (const float*)d_in[8];
    const float* alpha = (const float*)d_in[9];

    char* ws = (char*)d_ws;
    const size_t MB = 1024 * 1024;
    bf16* wqkv_h = (bf16*)(ws);              // 6 MB
    bf16* wqkv_l = (bf16*)(ws + 6 * MB);     // 6 MB
    bf16* wo_h   = (bf16*)(ws + 12 * MB);    // 2 MB
    float* knG   = (float*)(ws + 14 * MB);   // 0.25 MB (65536 floats)
    bf16* x_h    = (bf16*)(ws + 16 * MB);    // 8 MB
    bf16* x_l    = (bf16*)(ws + 24 * MB);    // 8 MB
    bf16* Q_h    = (bf16*)(ws + 32 * MB);    // 8 MB
    bf16* Q_l    = (bf16*)(ws + 40 * MB);    // 8 MB
    bf16* K_h    = (bf16*)(ws + 48 * MB);    // 8 MB
    bf16* K_l    = (bf16*)(ws + 56 * MB);    // 8 MB
    bf16* Vt_g   = (bf16*)(ws + 64 * MB);    // 8 MB, [B,H,D,S]
    bf16* Ob     = (bf16*)(ws);              // aliases wqkv (dead after QKV GEMM)

    split_x<<<dim3(2048), 256, 0, stream>>>(x, x_h, x_l);
    transpose_w<<<dim3(32, 32, 4), dim3(32, 8), 0, stream>>>(
        wq, wk, wv, wo, wqkv_h, wqkv_l, wo_h);
    gemm_qkv3<<<dim3(32, 24), 256, 0, stream>>>(
        x_h, x_l, wqkv_h, wqkv_l, bq, bk, bv, Q_h, Q_l, K_h, K_l, Vt_g);
    kn_kernel<<<dim3(256), 256, 0, stream>>>(K_h, K_l, knG);
    attn_kernel<<<dim3(32, 16), 256, 0, stream>>>(
        Q_h, Q_l, K_h, K_l, Vt_g, knG, Ob, alpha);
    gemm_out<<<dim3(32, 8), 256, 0, stream>>>(Ob, wo_h, bo, (float*)d_out);
}

// Round 6
// 293.750 us; speedup vs baseline: 1.4918x; 1.0250x over previous
//
#include <hip/hip_runtime.h>
#include <hip/hip_bf16.h>
#include <math.h>

typedef __bf16 bf16;
typedef bf16 bf16x4 __attribute__((ext_vector_type(4)));
typedef bf16 bf16x8 __attribute__((ext_vector_type(8)));
typedef float floatx4 __attribute__((ext_vector_type(4)));

#define MFMA16(a, b, c) __builtin_amdgcn_mfma_f32_16x16x32_bf16(a, b, c, 0, 0, 0)

__device__ __forceinline__ void split2(float v, bf16& h, bf16& l) {
    h = (bf16)v;
    l = (bf16)(v - (float)h);
}

// async global->LDS, 16 B per lane; LDS dest = wave-uniform base + lane*16
__device__ __forceinline__ void gload16(const bf16* g, bf16* l) {
    __builtin_amdgcn_global_load_lds(
        (const __attribute__((address_space(1))) void*)g,
        (__attribute__((address_space(3))) void*)l, 16, 0, 0);
}

// ---------------------------------------------------------------------------
// K0a: split x fp32 -> hi/lo bf16 (same layout)
// ---------------------------------------------------------------------------
__global__ void split_x(const float* __restrict__ x, bf16* __restrict__ xh,
                        bf16* __restrict__ xl) {
    const int i = (blockIdx.x * 256 + threadIdx.x) * 8;
    float4 a = *(const float4*)(x + i);
    float4 b = *(const float4*)(x + i + 4);
    bf16x8 oh, ol;
    float f[8] = {a.x, a.y, a.z, a.w, b.x, b.y, b.z, b.w};
#pragma unroll
    for (int j = 0; j < 8; j++) { bf16 h, l; split2(f[j], h, l); oh[j] = h; ol[j] = l; }
    *(bf16x8*)(xh + i) = oh;
    *(bf16x8*)(xl + i) = ol;
}

// ---------------------------------------------------------------------------
// K0b: transpose+split the 4 fp32 weights [1024][1024] W[k][n] -> hi/lo bf16 Wt[n][k]
// ---------------------------------------------------------------------------
__global__ void transpose_w(const float* __restrict__ wq, const float* __restrict__ wk,
                            const float* __restrict__ wv, const float* __restrict__ wo,
                            bf16* __restrict__ wt_qkv_h, bf16* __restrict__ wt_qkv_l,
                            bf16* __restrict__ wt_o_h) {
    const int z = blockIdx.z;
    const float* src = (z == 0) ? wq : (z == 1) ? wk : (z == 2) ? wv : wo;
    bf16* dsth = (z < 3) ? (wt_qkv_h + (size_t)z * 1024 * 1024) : wt_o_h;
    bf16* dstl = (z < 3) ? (wt_qkv_l + (size_t)z * 1024 * 1024) : nullptr;
    __shared__ float tile[32][33];
    const int x0 = blockIdx.x * 32, y0 = blockIdx.y * 32;
    const int tx = threadIdx.x, ty = threadIdx.y;  // (32,8)
    for (int i = 0; i < 32; i += 8)
        tile[ty + i][tx] = src[(size_t)(y0 + ty + i) * 1024 + x0 + tx];
    __syncthreads();
    for (int i = 0; i < 32; i += 8) {
        bf16 h, l;
        split2(tile[tx][ty + i], h, l);
        dsth[(size_t)(x0 + ty + i) * 1024 + y0 + tx] = h;
        if (dstl) dstl[(size_t)(x0 + ty + i) * 1024 + y0 + tx] = l;
    }
}

// ---------------------------------------------------------------------------
// K1: fused QKV GEMM, split-bf16, m97-style global_load_lds staging.
// C = A * Bt^T + bias.  N=3072.  Unpadded 128x32 LDS tiles (BK=32).
// Q,K slabs: 3-term (fp32-accurate) -> hi/lo pairs [B,H,S,D].
// V slab: 1-term -> TRANSPOSED Vt[B,H,D,S].
// ---------------------------------------------------------------------------
__global__ __launch_bounds__(256, 2) void gemm_qkv3(
    const bf16* __restrict__ Ah, const bf16* __restrict__ Al,
    const bf16* __restrict__ Bth, const bf16* __restrict__ Btl,
    const float* __restrict__ bq, const float* __restrict__ bk,
    const float* __restrict__ bv,
    bf16* __restrict__ Qh, bf16* __restrict__ Ql,
    bf16* __restrict__ Kh, bf16* __restrict__ Kl, bf16* __restrict__ VtG) {
    __shared__ bf16 Ash[128 * 32];
    __shared__ bf16 Asl[128 * 32];
    __shared__ bf16 Bsh[128 * 32];
    __shared__ bf16 Bsl[128 * 32];

    const int t = threadIdx.x;
    const int lane = t & 63, wave = t >> 6;
    const int quad = lane >> 4, l16 = lane & 15;
    const int m0 = blockIdx.x * 128, n0 = blockIdx.y * 128;
    const int wm = (wave >> 1) * 64, wn = (wave & 1) * 64;
    const bool full = (n0 < 2048);  // Q/K slabs need the low-order terms

    // staging map: wave stages 16 rows per issue; lane -> (row=ln>>2, col=(ln&3)*8)
    const int srow = wave * 16 + (lane >> 2);   // rows for it=0; +64 for it=1
    const int scol = (lane & 3) * 8;
    const bf16* gAh = Ah + (size_t)(m0 + srow) * 1024 + scol;
    const bf16* gAl = Al + (size_t)(m0 + srow) * 1024 + scol;
    const bf16* gBh = Bth + (size_t)(n0 + srow) * 1024 + scol;
    const bf16* gBl = Btl + (size_t)(n0 + srow) * 1024 + scol;
    bf16* lAh = &Ash[wave * 16 * 32];
    bf16* lAl = &Asl[wave * 16 * 32];
    bf16* lBh = &Bsh[wave * 16 * 32];
    bf16* lBl = &Bsl[wave * 16 * 32];

    floatx4 acc[4][4] = {};

    for (int k0 = 0; k0 < 1024; k0 += 32) {
        // async stage tile k0 (prev iteration's trailing barrier protects LDS)
        gload16(gAh + k0, lAh);
        gload16(gAh + 64 * 1024 + k0, lAh + 64 * 32);
        gload16(gBh + k0, lBh);
        gload16(gBh + 64 * 1024 + k0, lBh + 64 * 32);
        if (full) {
            gload16(gAl + k0, lAl);
            gload16(gAl + 64 * 1024 + k0, lAl + 64 * 32);
            gload16(gBl + k0, lBl);
            gload16(gBl + 64 * 1024 + k0, lBl + 64 * 32);
        }
        __syncthreads();  // drains vmcnt -> tile visible to all waves
        bf16x8 afh[4], bfh[4];
#pragma unroll
        for (int i = 0; i < 4; i++)
            afh[i] = *(bf16x8*)&Ash[(wm + i * 16 + l16) * 32 + quad * 8];
#pragma unroll
        for (int j = 0; j < 4; j++)
            bfh[j] = *(bf16x8*)&Bsh[(wn + j * 16 + l16) * 32 + quad * 8];
        if (full) {
            bf16x8 afl[4], bfl[4];
#pragma unroll
            for (int i = 0; i < 4; i++)
                afl[i] = *(bf16x8*)&Asl[(wm + i * 16 + l16) * 32 + quad * 8];
#pragma unroll
            for (int j = 0; j < 4; j++)
                bfl[j] = *(bf16x8*)&Bsl[(wn + j * 16 + l16) * 32 + quad * 8];
#pragma unroll
            for (int i = 0; i < 4; i++)
#pragma unroll
                for (int j = 0; j < 4; j++) {
                    acc[i][j] = MFMA16(afh[i], bfh[j], acc[i][j]);
                    acc[i][j] = MFMA16(afh[i], bfl[j], acc[i][j]);
                    acc[i][j] = MFMA16(afl[i], bfh[j], acc[i][j]);
                }
        } else {
#pragma unroll
            for (int i = 0; i < 4; i++)
#pragma unroll
                for (int j = 0; j < 4; j++)
                    acc[i][j] = MFMA16(afh[i], bfh[j], acc[i][j]);
        }
        __syncthreads();  // all reads done before next iteration's stores
    }

    const int which = n0 >> 10;  // 0=Q 1=K 2=V (128 | 1024, never straddles)
    const float* bias = (which == 0) ? bq : (which == 1) ? bk : bv;
#pragma unroll
    for (int i = 0; i < 4; i++)
#pragma unroll
        for (int j = 0; j < 4; j++) {
            const int col = n0 + wn + j * 16 + l16;
            const int o = col & 1023;
            const int h = o >> 6, d = o & 63;
            const float bvv = bias[o];
            const int gm0 = m0 + wm + i * 16 + quad * 4;  // token id of r=0
            const int b = gm0 >> 11;
            if (which == 2) {
                bf16x4 pv;
#pragma unroll
                for (int r = 0; r < 4; r++) pv[r] = (bf16)(acc[i][j][r] + bvv);
                const int s0 = gm0 & 2047;
                *(bf16x4*)&VtG[((size_t)((b * 16 + h) * 64 + d)) * 2048 + s0] = pv;
            } else {
#pragma unroll
                for (int r = 0; r < 4; r++) {
                    const int gm = gm0 + r;
                    const int s = gm & 2047;
                    const size_t idx = (size_t)((b * 16 + h) * 2048 + s) * 64 + d;
                    const float val = acc[i][j][r] + bvv;
                    bf16 hi, lo;
                    split2(val, hi, lo);
                    if (which == 0) { Qh[idx] = hi; Ql[idx] = lo; }
                    else            { Kh[idx] = hi; Kl[idx] = lo; }
                }
            }
        }
}

// ---------------------------------------------------------------------------
// K1b: precompute ||k||^2 per key row (fp32 from hi+lo), knG[bh*2048+s]
// ---------------------------------------------------------------------------
__global__ void kn_kernel(const bf16* __restrict__ Kh, const bf16* __restrict__ Kl,
                          float* __restrict__ knG) {
    const int i = blockIdx.x * 256 + threadIdx.x;  // 0..65535
    const bf16* ph = Kh + (size_t)i * 64;
    const bf16* pl = Kl + (size_t)i * 64;
    float s = 0.f;
#pragma unroll
    for (int d0 = 0; d0 < 64; d0 += 8) {
        bf16x8 vh = *(const bf16x8*)(ph + d0);
        bf16x8 vl = *(const bf16x8*)(pl + d0);
#pragma unroll
        for (int j = 0; j < 8; j++) { float x = (float)vh[j] + (float)vl[j]; s += x * x; }
    }
    knG[i] = s;
}

// ---------------------------------------------------------------------------
// K2: flash attention, YAT scores, transposed orientation, 32 q per wave.
//   S^T = K·Q^T (3-term split), online softmax per q-column (lane-local),
//   O^T = V^T·P^T.  Block = 4 waves = 128 q; chunks of 64 keys.
// ---------------------------------------------------------------------------
__global__ __launch_bounds__(256, 2) void attn_kernel(
    const bf16* __restrict__ Qh, const bf16* __restrict__ Ql,
    const bf16* __restrict__ Kh, const bf16* __restrict__ Kl,
    const bf16* __restrict__ VtG, const float* __restrict__ knG,
    bf16* __restrict__ O, const float* __restrict__ alphap) {
    __shared__ bf16 Ksh[64 * 72];     // [key][d] hi
    __shared__ bf16 Ksl[64 * 72];     // [key][d] lo
    __shared__ bf16 Vs[64 * 72];      // [d][key]
    __shared__ bf16 Pt[4][32 * 72];   // per-wave P [q][key], stride 72
    __shared__ float knL[64];

    const int t = threadIdx.x, lane = t & 63, wave = t >> 6;
    const int quad = lane >> 4, l16 = lane & 15;
    const int bh = blockIdx.x;        // b*16+h
    const int qw = blockIdx.y * 128 + wave * 32;  // wave's first q

    const float alpha = alphap[0];
    // fold sc and log2(e) into the score so softmax uses raw exp2
    const float C = powf(8.0f / log1pf(64.0f), alpha) * 1.44269504f;

    // Q^T B-fragments (hi+lo), 2 q-groups of 16: B[k=d][n=q]
    const size_t qrow0 = ((size_t)bh * 2048 + qw + l16) * 64;
    const size_t qrow1 = qrow0 + 16 * 64;
    bf16x8 bq0h[2], bq1h[2], bq0l[2], bq1l[2];
    bq0h[0] = *(const bf16x8*)(Qh + qrow0 + quad * 8);
    bq1h[0] = *(const bf16x8*)(Qh + qrow0 + 32 + quad * 8);
    bq0l[0] = *(const bf16x8*)(Ql + qrow0 + quad * 8);
    bq1l[0] = *(const bf16x8*)(Ql + qrow0 + 32 + quad * 8);
    bq0h[1] = *(const bf16x8*)(Qh + qrow1 + quad * 8);
    bq1h[1] = *(const bf16x8*)(Qh + qrow1 + 32 + quad * 8);
    bq0l[1] = *(const bf16x8*)(Ql + qrow1 + quad * 8);
    bq1l[1] = *(const bf16x8*)(Ql + qrow1 + 32 + quad * 8);

    // ||q||^2 per q-group (lane-local 16 d + quad reduce), eps folded in
    float qne[2];
#pragma unroll
    for (int qg = 0; qg < 2; qg++) {
        float qn = 0.f;
#pragma unroll
        for (int j = 0; j < 8; j++) {
            float x0 = (float)bq0h[qg][j] + (float)bq0l[qg][j];
            float x1 = (float)bq1h[qg][j] + (float)bq1l[qg][j];
            qn += x0 * x0 + x1 * x1;
        }
        qn += __shfl_xor(qn, 16, 64);
        qn += __shfl_xor(qn, 32, 64);
        qne[qg] = qn + 1e-5f;
    }

    floatx4 acco[2][4] = {};          // O^T per qg: row d=dsub*16+quad*4+r, col q=l16
    float m_i[2] = {0.f, 0.f};        // scores >= 0 (exp2 domain)
    float l_i[2] = {0.f, 0.f};

    const int srow = t >> 3;          // 0..31
    const int scol = (t & 7) * 8;     // 0..56
    const size_t vrow0 = ((size_t)bh * 64 + srow) * 2048;
    const size_t vrow1 = ((size_t)bh * 64 + srow + 32) * 2048;
    const float* knB = knG + (size_t)bh * 2048;

    for (int kc = 0; kc < 2048; kc += 64) {
        const size_t kbase = (size_t)(bh * 2048 + kc) * 64;
        bf16x8 kh0 = *(const bf16x8*)(Kh + kbase + srow * 64 + scol);
        bf16x8 kh1 = *(const bf16x8*)(Kh + kbase + (32 + srow) * 64 + scol);
        bf16x8 kl0 = *(const bf16x8*)(Kl + kbase + srow * 64 + scol);
        bf16x8 kl1 = *(const bf16x8*)(Kl + kbase + (32 + srow) * 64 + scol);
        bf16x8 v0 = *(const bf16x8*)(VtG + vrow0 + kc + scol);
        bf16x8 v1 = *(const bf16x8*)(VtG + vrow1 + kc + scol);
        __syncthreads();  // previous chunk's LDS reads complete
        *(bf16x8*)&Ksh[srow * 72 + scol] = kh0;
        *(bf16x8*)&Ksh[(32 + srow) * 72 + scol] = kh1;
        *(bf16x8*)&Ksl[srow * 72 + scol] = kl0;
        *(bf16x8*)&Ksl[(32 + srow) * 72 + scol] = kl1;
        *(bf16x8*)&Vs[srow * 72 + scol] = v0;
        *(bf16x8*)&Vs[(32 + srow) * 72 + scol] = v1;
        if (t < 16) *(float4*)&knL[t * 4] = *(const float4*)(knB + kc + t * 4);
        __syncthreads();

        // S^T = K·Q^T (split 3-term) -> YAT scores (exp2-scaled)
        float pbuf[2][4][4];
        float mloc[2] = {0.f, 0.f};
#pragma unroll
        for (int sub = 0; sub < 4; sub++) {
            bf16x8 a0h = *(bf16x8*)&Ksh[(sub * 16 + l16) * 72 + quad * 8];
            bf16x8 a1h = *(bf16x8*)&Ksh[(sub * 16 + l16) * 72 + 32 + quad * 8];
            bf16x8 a0l = *(bf16x8*)&Ksl[(sub * 16 + l16) * 72 + quad * 8];
            bf16x8 a1l = *(bf16x8*)&Ksl[(sub * 16 + l16) * 72 + 32 + quad * 8];
            floatx4 ac0 = {}, ac1 = {};
            ac0 = MFMA16(a0h, bq0h[0], ac0);
            ac0 = MFMA16(a1h, bq1h[0], ac0);
            ac0 = MFMA16(a0h, bq0l[0], ac0);
            ac0 = MFMA16(a1h, bq1l[0], ac0);
            ac0 = MFMA16(a0l, bq0h[0], ac0);
            ac0 = MFMA16(a1l, bq1h[0], ac0);
            ac1 = MFMA16(a0h, bq0h[1], ac1);
            ac1 = MFMA16(a1h, bq1h[1], ac1);
            ac1 = MFMA16(a0h, bq0l[1], ac1);
            ac1 = MFMA16(a1h, bq1l[1], ac1);
            ac1 = MFMA16(a0l, bq0h[1], ac1);
            ac1 = MFMA16(a1l, bq1h[1], ac1);
            const floatx4 knv = *(const floatx4*)&knL[sub * 16 + quad * 4];
#pragma unroll
            for (int r = 0; r < 4; r++) {
                const float d0 = ac0[r];
                const float d1 = ac1[r];
                const float e0 = fmaf(-2.0f, d0, qne[0] + knv[r]);
                const float e1 = fmaf(-2.0f, d1, qne[1] + knv[r]);
                const float s0 = C * d0 * d0 * __builtin_amdgcn_rcpf(e0);
                const float s1 = C * d1 * d1 * __builtin_amdgcn_rcpf(e1);
                pbuf[0][sub][r] = s0;
                pbuf[1][sub][r] = s1;
                mloc[0] = fmaxf(mloc[0], s0);
                mloc[1] = fmaxf(mloc[1], s1);
            }
        }

        // online softmax per q-column + P writes (b64, [q][key])
        bf16* Pw = Pt[wave];
#pragma unroll
        for (int qg = 0; qg < 2; qg++) {
            float mx = mloc[qg];
            mx = fmaxf(mx, __shfl_xor(mx, 16, 64));
            mx = fmaxf(mx, __shfl_xor(mx, 32, 64));
            const float mnew = fmaxf(m_i[qg], mx);
            const float al = __builtin_amdgcn_exp2f(m_i[qg] - mnew);
            float rs = 0.f;
            bf16* Pq = Pw + (qg * 16 + l16) * 72;
#pragma unroll
            for (int sub = 0; sub < 4; sub++) {
                bf16x4 pv;
#pragma unroll
                for (int r = 0; r < 4; r++) {
                    const float p = __builtin_amdgcn_exp2f(pbuf[qg][sub][r] - mnew);
                    rs += p;
                    pv[r] = (bf16)p;
                }
                *(bf16x4*)&Pq[sub * 16 + quad * 4] = pv;
            }
            rs += __shfl_xor(rs, 16, 64);
            rs += __shfl_xor(rs, 32, 64);
            l_i[qg] = l_i[qg] * al + rs;
            m_i[qg] = mnew;
#pragma unroll
            for (int dsub = 0; dsub < 4; dsub++) acco[qg][dsub] *= al;
        }

        // O^T += V^T·P^T (same-wave Pt round-trip; b128 B-frag reads)
        bf16x8 bp0[2], bp1[2];
#pragma unroll
        for (int qg = 0; qg < 2; qg++) {
            bp0[qg] = *(bf16x8*)&Pw[(qg * 16 + l16) * 72 + quad * 8];
            bp1[qg] = *(bf16x8*)&Pw[(qg * 16 + l16) * 72 + 32 + quad * 8];
        }
#pragma unroll
        for (int dsub = 0; dsub < 4; dsub++) {
            bf16x8 a0 = *(bf16x8*)&Vs[(dsub * 16 + l16) * 72 + quad * 8];
            bf16x8 a1 = *(bf16x8*)&Vs[(dsub * 16 + l16) * 72 + 32 + quad * 8];
            acco[0][dsub] = MFMA16(a0, bp0[0], acco[0][dsub]);
            acco[0][dsub] = MFMA16(a1, bp1[0], acco[0][dsub]);
            acco[1][dsub] = MFMA16(a0, bp0[1], acco[1][dsub]);
            acco[1][dsub] = MFMA16(a1, bp1[1], acco[1][dsub]);
        }
    }

    // epilogue: O[b][s][h*64+d]; 4 r-values are d-contiguous -> b64 stores
    const int b = bh >> 4, h = bh & 15;
#pragma unroll
    for (int qg = 0; qg < 2; qg++) {
        const int s = qw + qg * 16 + l16;
        const float rl = 1.0f / l_i[qg];
        const size_t obase = (size_t)(b * 2048 + s) * 1024 + h * 64;
#pragma unroll
        for (int dsub = 0; dsub < 4; dsub++) {
            bf16x4 ov;
#pragma unroll
            for (int r = 0; r < 4; r++) ov[r] = (bf16)(acco[qg][dsub][r] * rl);
            *(bf16x4*)&O[obase + dsub * 16 + quad * 4] = ov;
        }
    }
}

// ---------------------------------------------------------------------------
// K3: out-proj GEMM (single bf16 pass, m97-style staging), fp32 output
// ---------------------------------------------------------------------------
__global__ __launch_bounds__(256, 2) void gemm_out(
    const bf16* __restrict__ A, const bf16* __restrict__ Bt,
    const float* __restrict__ bias, float* __restrict__ outC) {
    __shared__ bf16 As[128 * 32];
    __shared__ bf16 Bs[128 * 32];

    const int t = threadIdx.x;
    const int lane = t & 63, wave = t >> 6;
    const int quad = lane >> 4, l16 = lane & 15;
    const int m0 = blockIdx.x * 128, n0 = blockIdx.y * 128;
    const int wm = (wave >> 1) * 64, wn = (wave & 1) * 64;

    const int srow = wave * 16 + (lane >> 2);
    const int scol = (lane & 3) * 8;
    const bf16* gA0 = A + (size_t)(m0 + srow) * 1024 + scol;
    const bf16* gB0 = Bt + (size_t)(n0 + srow) * 1024 + scol;
    bf16* lA = &As[wave * 16 * 32];
    bf16* lB = &Bs[wave * 16 * 32];

    floatx4 acc[4][4] = {};

    for (int k0 = 0; k0 < 1024; k0 += 32) {
        gload16(gA0 + k0, lA);
        gload16(gA0 + 64 * 1024 + k0, lA + 64 * 32);
        gload16(gB0 + k0, lB);
        gload16(gB0 + 64 * 1024 + k0, lB + 64 * 32);
        __syncthreads();
        bf16x8 af[4], bf_[4];
#pragma unroll
        for (int i = 0; i < 4; i++)
            af[i] = *(bf16x8*)&As[(wm + i * 16 + l16) * 32 + quad * 8];
#pragma unroll
        for (int j = 0; j < 4; j++)
            bf_[j] = *(bf16x8*)&Bs[(wn + j * 16 + l16) * 32 + quad * 8];
#pragma unroll
        for (int i = 0; i < 4; i++)
#pragma unroll
            for (int j = 0; j < 4; j++)
                acc[i][j] = MFMA16(af[i], bf_[j], acc[i][j]);
        __syncthreads();
    }

#pragma unroll
    for (int i = 0; i < 4; i++)
#pragma unroll
        for (int j = 0; j < 4; j++) {
            const int col = n0 + wn + j * 16 + l16;
            const float bvv = bias[col];
#pragma unroll
            for (int r = 0; r < 4; r++) {
                const int gm = m0 + wm + i * 16 + quad * 4 + r;
                outC[(size_t)gm * 1024 + col] = acc[i][j][r] + bvv;
            }
        }
}

// ---------------------------------------------------------------------------
extern "C" void kernel_launch(void* const* d_in, const int* in_sizes, int n_in,
                              void* d_out, int out_size, void* d_ws, size_t ws_size,
                              hipStream_t stream) {
    const float* x  = (const float*)d_in[0];
    const float* wq = (const float*)d_in[1];
    const float* bq = (const float*)d_in[2];
    const float* wk = (const float*)d_in[3];
    const float* bk = (const float*)d_in[4];
    const float* wv = (const float*)d_in[5];
    const float* bv = (const float*)d_in[6];
    const float* wo = (const float*)d_in[7];
    const float* bo = (const float*)d_in[8];
    const float* alpha = (const float*)d_in[9];

    char* ws = (char*)d_ws;
    const size_t MB = 1024 * 1024;
    bf16* wqkv_h = (bf16*)(ws);              // 6 MB
    bf16* wqkv_l = (bf16*)(ws + 6 * MB);     // 6 MB
    bf16* wo_h   = (bf16*)(ws + 12 * MB);    // 2 MB
    float* knG   = (float*)(ws + 14 * MB);   // 0.25 MB (65536 floats)
    bf16* x_h    = (bf16*)(ws + 16 * MB);    // 8 MB
    bf16* x_l    = (bf16*)(ws + 24 * MB);    // 8 MB
    bf16* Q_h    = (bf16*)(ws + 32 * MB);    // 8 MB
    bf16* Q_l    = (bf16*)(ws + 40 * MB);    // 8 MB
    bf16* K_h    = (bf16*)(ws + 48 * MB);    // 8 MB
    bf16* K_l    = (bf16*)(ws + 56 * MB);    // 8 MB
    bf16* Vt_g   = (bf16*)(ws + 64 * MB);    // 8 MB, [B,H,D,S]
    bf16* Ob     = (bf16*)(ws);              // aliases wqkv (dead after QKV GEMM)

    split_x<<<dim3(2048), 256, 0, stream>>>(x, x_h, x_l);
    transpose_w<<<dim3(32, 32, 4), dim3(32, 8), 0, stream>>>(
        wq, wk, wv, wo, wqkv_h, wqkv_l, wo_h);
    gemm_qkv3<<<dim3(32, 24), 256, 0, stream>>>(
        x_h, x_l, wqkv_h, wqkv_l, bq, bk, bv, Q_h, Q_l, K_h, K_l, Vt_g);
    kn_kernel<<<dim3(256), 256, 0, stream>>>(K_h, K_l, knG);
    attn_kernel<<<dim3(32, 16), 256, 0, stream>>>(
        Q_h, Q_l, K_h, K_l, Vt_g, knG, Ob, alpha);
    gemm_out<<<dim3(32, 8), 256, 0, stream>>>(Ob, wo_h, bo, (float*)d_out);
}

// Round 7
// 293.126 us; speedup vs baseline: 1.4950x; 1.0021x over previous
//
#include <hip/hip_runtime.h>
#include <hip/hip_bf16.h>
#include <math.h>

typedef __bf16 bf16;
typedef bf16 bf16x4 __attribute__((ext_vector_type(4)));
typedef bf16 bf16x8 __attribute__((ext_vector_type(8)));
typedef float floatx4 __attribute__((ext_vector_type(4)));

#define MFMA16(a, b, c) __builtin_amdgcn_mfma_f32_16x16x32_bf16(a, b, c, 0, 0, 0)

__device__ __forceinline__ void split2(float v, bf16& h, bf16& l) {
    h = (bf16)v;
    l = (bf16)(v - (float)h);
}

// async global->LDS, 16 B per lane; LDS dest = wave-uniform base + lane*16
__device__ __forceinline__ void gload16(const bf16* g, bf16* l) {
    __builtin_amdgcn_global_load_lds(
        (const __attribute__((address_space(1))) void*)g,
        (__attribute__((address_space(3))) void*)l, 16, 0, 0);
}

// ---------------------------------------------------------------------------
// K0a: split x fp32 -> hi/lo bf16 (same layout)
// ---------------------------------------------------------------------------
__global__ void split_x(const float* __restrict__ x, bf16* __restrict__ xh,
                        bf16* __restrict__ xl) {
    const int i = (blockIdx.x * 256 + threadIdx.x) * 8;
    float4 a = *(const float4*)(x + i);
    float4 b = *(const float4*)(x + i + 4);
    bf16x8 oh, ol;
    float f[8] = {a.x, a.y, a.z, a.w, b.x, b.y, b.z, b.w};
#pragma unroll
    for (int j = 0; j < 8; j++) { bf16 h, l; split2(f[j], h, l); oh[j] = h; ol[j] = l; }
    *(bf16x8*)(xh + i) = oh;
    *(bf16x8*)(xl + i) = ol;
}

// ---------------------------------------------------------------------------
// K0b: transpose+split the 4 fp32 weights [1024][1024] W[k][n] -> hi/lo bf16 Wt[n][k]
// ---------------------------------------------------------------------------
__global__ void transpose_w(const float* __restrict__ wq, const float* __restrict__ wk,
                            const float* __restrict__ wv, const float* __restrict__ wo,
                            bf16* __restrict__ wt_qkv_h, bf16* __restrict__ wt_qkv_l,
                            bf16* __restrict__ wt_o_h) {
    const int z = blockIdx.z;
    const float* src = (z == 0) ? wq : (z == 1) ? wk : (z == 2) ? wv : wo;
    bf16* dsth = (z < 3) ? (wt_qkv_h + (size_t)z * 1024 * 1024) : wt_o_h;
    bf16* dstl = (z < 3) ? (wt_qkv_l + (size_t)z * 1024 * 1024) : nullptr;
    __shared__ float tile[32][33];
    const int x0 = blockIdx.x * 32, y0 = blockIdx.y * 32;
    const int tx = threadIdx.x, ty = threadIdx.y;  // (32,8)
    for (int i = 0; i < 32; i += 8)
        tile[ty + i][tx] = src[(size_t)(y0 + ty + i) * 1024 + x0 + tx];
    __syncthreads();
    for (int i = 0; i < 32; i += 8) {
        bf16 h, l;
        split2(tile[tx][ty + i], h, l);
        dsth[(size_t)(x0 + ty + i) * 1024 + y0 + tx] = h;
        if (dstl) dstl[(size_t)(x0 + ty + i) * 1024 + y0 + tx] = l;
    }
}

// ---------------------------------------------------------------------------
// K1: fused QKV GEMM, split-bf16, m97-style global_load_lds staging.
// ---------------------------------------------------------------------------
__global__ __launch_bounds__(256, 2) void gemm_qkv3(
    const bf16* __restrict__ Ah, const bf16* __restrict__ Al,
    const bf16* __restrict__ Bth, const bf16* __restrict__ Btl,
    const float* __restrict__ bq, const float* __restrict__ bk,
    const float* __restrict__ bv,
    bf16* __restrict__ Qh, bf16* __restrict__ Ql,
    bf16* __restrict__ Kh, bf16* __restrict__ Kl, bf16* __restrict__ VtG) {
    __shared__ bf16 Ash[128 * 32];
    __shared__ bf16 Asl[128 * 32];
    __shared__ bf16 Bsh[128 * 32];
    __shared__ bf16 Bsl[128 * 32];

    const int t = threadIdx.x;
    const int lane = t & 63, wave = t >> 6;
    const int quad = lane >> 4, l16 = lane & 15;
    const int m0 = blockIdx.x * 128, n0 = blockIdx.y * 128;
    const int wm = (wave >> 1) * 64, wn = (wave & 1) * 64;
    const bool full = (n0 < 2048);

    const int srow = wave * 16 + (lane >> 2);
    const int scol = (lane & 3) * 8;
    const bf16* gAh = Ah + (size_t)(m0 + srow) * 1024 + scol;
    const bf16* gAl = Al + (size_t)(m0 + srow) * 1024 + scol;
    const bf16* gBh = Bth + (size_t)(n0 + srow) * 1024 + scol;
    const bf16* gBl = Btl + (size_t)(n0 + srow) * 1024 + scol;
    bf16* lAh = &Ash[wave * 16 * 32];
    bf16* lAl = &Asl[wave * 16 * 32];
    bf16* lBh = &Bsh[wave * 16 * 32];
    bf16* lBl = &Bsl[wave * 16 * 32];

    floatx4 acc[4][4] = {};

    for (int k0 = 0; k0 < 1024; k0 += 32) {
        gload16(gAh + k0, lAh);
        gload16(gAh + 64 * 1024 + k0, lAh + 64 * 32);
        gload16(gBh + k0, lBh);
        gload16(gBh + 64 * 1024 + k0, lBh + 64 * 32);
        if (full) {
            gload16(gAl + k0, lAl);
            gload16(gAl + 64 * 1024 + k0, lAl + 64 * 32);
            gload16(gBl + k0, lBl);
            gload16(gBl + 64 * 1024 + k0, lBl + 64 * 32);
        }
        __syncthreads();
        bf16x8 afh[4], bfh[4];
#pragma unroll
        for (int i = 0; i < 4; i++)
            afh[i] = *(bf16x8*)&Ash[(wm + i * 16 + l16) * 32 + quad * 8];
#pragma unroll
        for (int j = 0; j < 4; j++)
            bfh[j] = *(bf16x8*)&Bsh[(wn + j * 16 + l16) * 32 + quad * 8];
        if (full) {
            bf16x8 afl[4], bfl[4];
#pragma unroll
            for (int i = 0; i < 4; i++)
                afl[i] = *(bf16x8*)&Asl[(wm + i * 16 + l16) * 32 + quad * 8];
#pragma unroll
            for (int j = 0; j < 4; j++)
                bfl[j] = *(bf16x8*)&Bsl[(wn + j * 16 + l16) * 32 + quad * 8];
#pragma unroll
            for (int i = 0; i < 4; i++)
#pragma unroll
                for (int j = 0; j < 4; j++) {
                    acc[i][j] = MFMA16(afh[i], bfh[j], acc[i][j]);
                    acc[i][j] = MFMA16(afh[i], bfl[j], acc[i][j]);
                    acc[i][j] = MFMA16(afl[i], bfh[j], acc[i][j]);
                }
        } else {
#pragma unroll
            for (int i = 0; i < 4; i++)
#pragma unroll
                for (int j = 0; j < 4; j++)
                    acc[i][j] = MFMA16(afh[i], bfh[j], acc[i][j]);
        }
        __syncthreads();
    }

    const int which = n0 >> 10;  // 0=Q 1=K 2=V
    const float* bias = (which == 0) ? bq : (which == 1) ? bk : bv;
#pragma unroll
    for (int i = 0; i < 4; i++)
#pragma unroll
        for (int j = 0; j < 4; j++) {
            const int col = n0 + wn + j * 16 + l16;
            const int o = col & 1023;
            const int h = o >> 6, d = o & 63;
            const float bvv = bias[o];
            const int gm0 = m0 + wm + i * 16 + quad * 4;
            const int b = gm0 >> 11;
            if (which == 2) {
                bf16x4 pv;
#pragma unroll
                for (int r = 0; r < 4; r++) pv[r] = (bf16)(acc[i][j][r] + bvv);
                const int s0 = gm0 & 2047;
                *(bf16x4*)&VtG[((size_t)((b * 16 + h) * 64 + d)) * 2048 + s0] = pv;
            } else {
#pragma unroll
                for (int r = 0; r < 4; r++) {
                    const int gm = gm0 + r;
                    const int s = gm & 2047;
                    const size_t idx = (size_t)((b * 16 + h) * 2048 + s) * 64 + d;
                    const float val = acc[i][j][r] + bvv;
                    bf16 hi, lo;
                    split2(val, hi, lo);
                    if (which == 0) { Qh[idx] = hi; Ql[idx] = lo; }
                    else            { Kh[idx] = hi; Kl[idx] = lo; }
                }
            }
        }
}

// ---------------------------------------------------------------------------
// K1b: precompute ||k||^2 per key row (fp32 from hi+lo), knG[bh*2048+s]
// ---------------------------------------------------------------------------
__global__ void kn_kernel(const bf16* __restrict__ Kh, const bf16* __restrict__ Kl,
                          float* __restrict__ knG) {
    const int i = blockIdx.x * 256 + threadIdx.x;
    const bf16* ph = Kh + (size_t)i * 64;
    const bf16* pl = Kl + (size_t)i * 64;
    float s = 0.f;
#pragma unroll
    for (int d0 = 0; d0 < 64; d0 += 8) {
        bf16x8 vh = *(const bf16x8*)(ph + d0);
        bf16x8 vl = *(const bf16x8*)(pl + d0);
#pragma unroll
        for (int j = 0; j < 8; j++) { float x = (float)vh[j] + (float)vl[j]; s += x * x; }
    }
    knG[i] = s;
}

// ---------------------------------------------------------------------------
// K2: flash attention, YAT scores, transposed orientation, 32 q per wave,
//   DOUBLE-BUFFERED K/V/kn staging: ONE barrier per 64-key chunk; chunk i+1's
//   global loads are in flight across all of chunk i's compute.
// ---------------------------------------------------------------------------
__global__ __launch_bounds__(256, 2) void attn_kernel(
    const bf16* __restrict__ Qh, const bf16* __restrict__ Ql,
    const bf16* __restrict__ Kh, const bf16* __restrict__ Kl,
    const bf16* __restrict__ VtG, const float* __restrict__ knG,
    bf16* __restrict__ O, const float* __restrict__ alphap) {
    __shared__ bf16 Ksh[2][64 * 72];   // [buf][key][d] hi
    __shared__ bf16 Ksl[2][64 * 72];   // [buf][key][d] lo
    __shared__ bf16 Vs[2][64 * 72];    // [buf][d][key]
    __shared__ bf16 Pt[4][32 * 72];    // per-wave P [q][key]
    __shared__ float knL[2][64];

    const int t = threadIdx.x, lane = t & 63, wave = t >> 6;
    const int quad = lane >> 4, l16 = lane & 15;
    const int bh = blockIdx.x;
    const int qw = blockIdx.y * 128 + wave * 32;

    const float alpha = alphap[0];
    const float C = powf(8.0f / log1pf(64.0f), alpha) * 1.44269504f;

    // Q^T B-fragments (hi+lo), 2 q-groups of 16
    const size_t qrow0 = ((size_t)bh * 2048 + qw + l16) * 64;
    const size_t qrow1 = qrow0 + 16 * 64;
    bf16x8 bq0h[2], bq1h[2], bq0l[2], bq1l[2];
    bq0h[0] = *(const bf16x8*)(Qh + qrow0 + quad * 8);
    bq1h[0] = *(const bf16x8*)(Qh + qrow0 + 32 + quad * 8);
    bq0l[0] = *(const bf16x8*)(Ql + qrow0 + quad * 8);
    bq1l[0] = *(const bf16x8*)(Ql + qrow0 + 32 + quad * 8);
    bq0h[1] = *(const bf16x8*)(Qh + qrow1 + quad * 8);
    bq1h[1] = *(const bf16x8*)(Qh + qrow1 + 32 + quad * 8);
    bq0l[1] = *(const bf16x8*)(Ql + qrow1 + quad * 8);
    bq1l[1] = *(const bf16x8*)(Ql + qrow1 + 32 + quad * 8);

    float qne[2];
#pragma unroll
    for (int qg = 0; qg < 2; qg++) {
        float qn = 0.f;
#pragma unroll
        for (int j = 0; j < 8; j++) {
            float x0 = (float)bq0h[qg][j] + (float)bq0l[qg][j];
            float x1 = (float)bq1h[qg][j] + (float)bq1l[qg][j];
            qn += x0 * x0 + x1 * x1;
        }
        qn += __shfl_xor(qn, 16, 64);
        qn += __shfl_xor(qn, 32, 64);
        qne[qg] = qn + 1e-5f;
    }

    floatx4 acco[2][4] = {};
    float m_i[2] = {0.f, 0.f};
    float l_i[2] = {0.f, 0.f};

    const int srow = t >> 3;
    const int scol = (t & 7) * 8;
    const size_t vrow0 = ((size_t)bh * 64 + srow) * 2048;
    const size_t vrow1 = ((size_t)bh * 64 + srow + 32) * 2048;
    const float* knB = knG + (size_t)bh * 2048;

    // chunk compute on buffer ib (everything else captured by reference)
    auto do_chunk = [&](int ib) {
        const bf16* KshC = Ksh[ib];
        const bf16* KslC = Ksl[ib];
        const bf16* VsC = Vs[ib];
        const float* knC = knL[ib];
        float pbuf[2][4][4];
        float mloc[2] = {0.f, 0.f};
#pragma unroll
        for (int sub = 0; sub < 4; sub++) {
            bf16x8 a0h = *(bf16x8*)&KshC[(sub * 16 + l16) * 72 + quad * 8];
            bf16x8 a1h = *(bf16x8*)&KshC[(sub * 16 + l16) * 72 + 32 + quad * 8];
            bf16x8 a0l = *(bf16x8*)&KslC[(sub * 16 + l16) * 72 + quad * 8];
            bf16x8 a1l = *(bf16x8*)&KslC[(sub * 16 + l16) * 72 + 32 + quad * 8];
            floatx4 ac0 = {}, ac1 = {};
            ac0 = MFMA16(a0h, bq0h[0], ac0);
            ac0 = MFMA16(a1h, bq1h[0], ac0);
            ac0 = MFMA16(a0h, bq0l[0], ac0);
            ac0 = MFMA16(a1h, bq1l[0], ac0);
            ac0 = MFMA16(a0l, bq0h[0], ac0);
            ac0 = MFMA16(a1l, bq1h[0], ac0);
            ac1 = MFMA16(a0h, bq0h[1], ac1);
            ac1 = MFMA16(a1h, bq1h[1], ac1);
            ac1 = MFMA16(a0h, bq0l[1], ac1);
            ac1 = MFMA16(a1h, bq1l[1], ac1);
            ac1 = MFMA16(a0l, bq0h[1], ac1);
            ac1 = MFMA16(a1l, bq1h[1], ac1);
            const floatx4 knv = *(const floatx4*)&knC[sub * 16 + quad * 4];
#pragma unroll
            for (int r = 0; r < 4; r++) {
                const float d0 = ac0[r];
                const float d1 = ac1[r];
                const float e0 = fmaf(-2.0f, d0, qne[0] + knv[r]);
                const float e1 = fmaf(-2.0f, d1, qne[1] + knv[r]);
                const float s0 = C * d0 * d0 * __builtin_amdgcn_rcpf(e0);
                const float s1 = C * d1 * d1 * __builtin_amdgcn_rcpf(e1);
                pbuf[0][sub][r] = s0;
                pbuf[1][sub][r] = s1;
                mloc[0] = fmaxf(mloc[0], s0);
                mloc[1] = fmaxf(mloc[1], s1);
            }
        }
        bf16* Pw = Pt[wave];
#pragma unroll
        for (int qg = 0; qg < 2; qg++) {
            float mx = mloc[qg];
            mx = fmaxf(mx, __shfl_xor(mx, 16, 64));
            mx = fmaxf(mx, __shfl_xor(mx, 32, 64));
            const float mnew = fmaxf(m_i[qg], mx);
            const float al = __builtin_amdgcn_exp2f(m_i[qg] - mnew);
            float rs = 0.f;
            bf16* Pq = Pw + (qg * 16 + l16) * 72;
#pragma unroll
            for (int sub = 0; sub < 4; sub++) {
                bf16x4 pv;
#pragma unroll
                for (int r = 0; r < 4; r++) {
                    const float p = __builtin_amdgcn_exp2f(pbuf[qg][sub][r] - mnew);
                    rs += p;
                    pv[r] = (bf16)p;
                }
                *(bf16x4*)&Pq[sub * 16 + quad * 4] = pv;
            }
            rs += __shfl_xor(rs, 16, 64);
            rs += __shfl_xor(rs, 32, 64);
            l_i[qg] = l_i[qg] * al + rs;
            m_i[qg] = mnew;
#pragma unroll
            for (int dsub = 0; dsub < 4; dsub++) acco[qg][dsub] *= al;
        }
        bf16x8 bp0[2], bp1[2];
#pragma unroll
        for (int qg = 0; qg < 2; qg++) {
            bp0[qg] = *(bf16x8*)&Pw[(qg * 16 + l16) * 72 + quad * 8];
            bp1[qg] = *(bf16x8*)&Pw[(qg * 16 + l16) * 72 + 32 + quad * 8];
        }
#pragma unroll
        for (int dsub = 0; dsub < 4; dsub++) {
            bf16x8 a0 = *(bf16x8*)&VsC[(dsub * 16 + l16) * 72 + quad * 8];
            bf16x8 a1 = *(bf16x8*)&VsC[(dsub * 16 + l16) * 72 + 32 + quad * 8];
            acco[0][dsub] = MFMA16(a0, bp0[0], acco[0][dsub]);
            acco[0][dsub] = MFMA16(a1, bp1[0], acco[0][dsub]);
            acco[1][dsub] = MFMA16(a0, bp0[1], acco[1][dsub]);
            acco[1][dsub] = MFMA16(a1, bp1[1], acco[1][dsub]);
        }
    };

    // prologue: stage chunk 0 into buf 0
    {
        const size_t kb = (size_t)(bh * 2048) * 64;
        bf16x8 k0 = *(const bf16x8*)(Kh + kb + srow * 64 + scol);
        bf16x8 k1 = *(const bf16x8*)(Kh + kb + (32 + srow) * 64 + scol);
        bf16x8 c0 = *(const bf16x8*)(Kl + kb + srow * 64 + scol);
        bf16x8 c1 = *(const bf16x8*)(Kl + kb + (32 + srow) * 64 + scol);
        bf16x8 v0 = *(const bf16x8*)(VtG + vrow0 + scol);
        bf16x8 v1 = *(const bf16x8*)(VtG + vrow1 + scol);
        *(bf16x8*)&Ksh[0][srow * 72 + scol] = k0;
        *(bf16x8*)&Ksh[0][(32 + srow) * 72 + scol] = k1;
        *(bf16x8*)&Ksl[0][srow * 72 + scol] = c0;
        *(bf16x8*)&Ksl[0][(32 + srow) * 72 + scol] = c1;
        *(bf16x8*)&Vs[0][srow * 72 + scol] = v0;
        *(bf16x8*)&Vs[0][(32 + srow) * 72 + scol] = v1;
        if (t < 16) *(float4*)&knL[0][t * 4] = *(const float4*)(knB + t * 4);
    }
    __syncthreads();

    // main loop: compute chunk ic on buf cur while loading chunk ic+1 into nxt
    for (int ic = 0; ic < 31; ic++) {
        const int cur = ic & 1, nxt = cur ^ 1;
        const int kc = (ic + 1) * 64;
        const size_t kb = (size_t)(bh * 2048 + kc) * 64;
        bf16x8 nk0 = *(const bf16x8*)(Kh + kb + srow * 64 + scol);
        bf16x8 nk1 = *(const bf16x8*)(Kh + kb + (32 + srow) * 64 + scol);
        bf16x8 nc0 = *(const bf16x8*)(Kl + kb + srow * 64 + scol);
        bf16x8 nc1 = *(const bf16x8*)(Kl + kb + (32 + srow) * 64 + scol);
        bf16x8 nv0 = *(const bf16x8*)(VtG + vrow0 + kc + scol);
        bf16x8 nv1 = *(const bf16x8*)(VtG + vrow1 + kc + scol);
        float4 nkn;
        if (t < 16) nkn = *(const float4*)(knB + kc + t * 4);

        do_chunk(cur);

        *(bf16x8*)&Ksh[nxt][srow * 72 + scol] = nk0;
        *(bf16x8*)&Ksh[nxt][(32 + srow) * 72 + scol] = nk1;
        *(bf16x8*)&Ksl[nxt][srow * 72 + scol] = nc0;
        *(bf16x8*)&Ksl[nxt][(32 + srow) * 72 + scol] = nc1;
        *(bf16x8*)&Vs[nxt][srow * 72 + scol] = nv0;
        *(bf16x8*)&Vs[nxt][(32 + srow) * 72 + scol] = nv1;
        if (t < 16) *(float4*)&knL[nxt][t * 4] = nkn;
        __syncthreads();
    }
    do_chunk(1);  // ic = 31 -> buf 1

    // epilogue: O[b][s][h*64+d]
    const int b = bh >> 4, h = bh & 15;
#pragma unroll
    for (int qg = 0; qg < 2; qg++) {
        const int s = qw + qg * 16 + l16;
        const float rl = 1.0f / l_i[qg];
        const size_t obase = (size_t)(b * 2048 + s) * 1024 + h * 64;
#pragma unroll
        for (int dsub = 0; dsub < 4; dsub++) {
            bf16x4 ov;
#pragma unroll
            for (int r = 0; r < 4; r++) ov[r] = (bf16)(acco[qg][dsub][r] * rl);
            *(bf16x4*)&O[obase + dsub * 16 + quad * 4] = ov;
        }
    }
}

// ---------------------------------------------------------------------------
// K3: out-proj GEMM (single bf16 pass, m97-style staging), fp32 output
// ---------------------------------------------------------------------------
__global__ __launch_bounds__(256, 2) void gemm_out(
    const bf16* __restrict__ A, const bf16* __restrict__ Bt,
    const float* __restrict__ bias, float* __restrict__ outC) {
    __shared__ bf16 As[128 * 32];
    __shared__ bf16 Bs[128 * 32];

    const int t = threadIdx.x;
    const int lane = t & 63, wave = t >> 6;
    const int quad = lane >> 4, l16 = lane & 15;
    const int m0 = blockIdx.x * 128, n0 = blockIdx.y * 128;
    const int wm = (wave >> 1) * 64, wn = (wave & 1) * 64;

    const int srow = wave * 16 + (lane >> 2);
    const int scol = (lane & 3) * 8;
    const bf16* gA0 = A + (size_t)(m0 + srow) * 1024 + scol;
    const bf16* gB0 = Bt + (size_t)(n0 + srow) * 1024 + scol;
    bf16* lA = &As[wave * 16 * 32];
    bf16* lB = &Bs[wave * 16 * 32];

    floatx4 acc[4][4] = {};

    for (int k0 = 0; k0 < 1024; k0 += 32) {
        gload16(gA0 + k0, lA);
        gload16(gA0 + 64 * 1024 + k0, lA + 64 * 32);
        gload16(gB0 + k0, lB);
        gload16(gB0 + 64 * 1024 + k0, lB + 64 * 32);
        __syncthreads();
        bf16x8 af[4], bf_[4];
#pragma unroll
        for (int i = 0; i < 4; i++)
            af[i] = *(bf16x8*)&As[(wm + i * 16 + l16) * 32 + quad * 8];
#pragma unroll
        for (int j = 0; j < 4; j++)
            bf_[j] = *(bf16x8*)&Bs[(wn + j * 16 + l16) * 32 + quad * 8];
#pragma unroll
        for (int i = 0; i < 4; i++)
#pragma unroll
            for (int j = 0; j < 4; j++)
                acc[i][j] = MFMA16(af[i], bf_[j], acc[i][j]);
        __syncthreads();
    }

#pragma unroll
    for (int i = 0; i < 4; i++)
#pragma unroll
        for (int j = 0; j < 4; j++) {
            const int col = n0 + wn + j * 16 + l16;
            const float bvv = bias[col];
#pragma unroll
            for (int r = 0; r < 4; r++) {
                const int gm = m0 + wm + i * 16 + quad * 4 + r;
                outC[(size_t)gm * 1024 + col] = acc[i][j][r] + bvv;
            }
        }
}

// ---------------------------------------------------------------------------
extern "C" void kernel_launch(void* const* d_in, const int* in_sizes, int n_in,
                              void* d_out, int out_size, void* d_ws, size_t ws_size,
                              hipStream_t stream) {
    const float* x  = (const float*)d_in[0];
    const float* wq = (const float*)d_in[1];
    const float* bq = (const float*)d_in[2];
    const float* wk = (const float*)d_in[3];
    const float* bk = (const float*)d_in[4];
    const float* wv = (const float*)d_in[5];
    const float* bv = (const float*)d_in[6];
    const float* wo = (const float*)d_in[7];
    const float* bo = (const float*)d_in[8];
    const float* alpha = (const float*)d_in[9];

    char* ws = (char*)d_ws;
    const size_t MB = 1024 * 1024;
    bf16* wqkv_h = (bf16*)(ws);              // 6 MB
    bf16* wqkv_l = (bf16*)(ws + 6 * MB);     // 6 MB
    bf16* wo_h   = (bf16*)(ws + 12 * MB);    // 2 MB
    float* knG   = (float*)(ws + 14 * MB);   // 0.25 MB
    bf16* x_h    = (bf16*)(ws + 16 * MB);    // 8 MB
    bf16* x_l    = (bf16*)(ws + 24 * MB);    // 8 MB
    bf16* Q_h    = (bf16*)(ws + 32 * MB);    // 8 MB
    bf16* Q_l    = (bf16*)(ws + 40 * MB);    // 8 MB
    bf16* K_h    = (bf16*)(ws + 48 * MB);    // 8 MB
    bf16* K_l    = (bf16*)(ws + 56 * MB);    // 8 MB
    bf16* Vt_g   = (bf16*)(ws + 64 * MB);    // 8 MB, [B,H,D,S]
    bf16* Ob     = (bf16*)(ws);              // aliases wqkv (dead after QKV GEMM)

    split_x<<<dim3(2048), 256, 0, stream>>>(x, x_h, x_l);
    transpose_w<<<dim3(32, 32, 4), dim3(32, 8), 0, stream>>>(
        wq, wk, wv, wo, wqkv_h, wqkv_l, wo_h);
    gemm_qkv3<<<dim3(32, 24), 256, 0, stream>>>(
        x_h, x_l, wqkv_h, wqkv_l, bq, bk, bv, Q_h, Q_l, K_h, K_l, Vt_g);
    kn_kernel<<<dim3(256), 256, 0, stream>>>(K_h, K_l, knG);
    attn_kernel<<<dim3(32, 16), 256, 0, stream>>>(
        Q_h, Q_l, K_h, K_l, Vt_g, knG, Ob, alpha);
    gemm_out<<<dim3(32, 8), 256, 0, stream>>>(Ob, wo_h, bo, (float*)d_out);
}